// Round 2
// baseline (33997.382 us; speedup 1.0000x reference)
//
#include <hip/hip_runtime.h>
#include <math.h>

// GRU-ODE / DCGRU on dense graph.  B=8, T=40, N=1024, DIN=16, DR=64, DH=64, K=3.
// dt = DT/N_EULER = 0.025, 2 Euler sub-steps per observation.
//
// Decomposition per timestep t (all fp32, round-1 correctness-first):
//   2x Euler:  HOP0: HH = [A;A2] @ S     (per state/batch, D=64)
//              ODE_TAIL: S += dt*tanh(tanh([S|Ah|A2h]@W0+b0)@Wout+bout)
//   OUT (t>=1): gate chain on zv_pre, X_pred slice written
//   HOP1: HH = [A;A2] @ [x|h]  ;  GATE_TAIL: r,u = sigmoid(feats@Wg+bg); RH=r*h; U=u
//   HOP2: HH = [A;A2] @ [x|rh] ;  CAND_TAIL: c=tanh(feats@Wc+bc); S = blend(h1, u*h1+(1-u)*c, m)
//
// ws layout (floats):
//   S  [16][1024][64]   @ 0          (i = state*8+b)
//   HH [16][2048][80]   @ 1048576
//   RH [16][1024][64]   @ 3670016
//   U  [16][1024][64]   @ 4718592
//   A2 [8][1024][1024]  @ 5767168
//   total 14,155,776 floats = 56.6 MB

#define T_ 40

__device__ __forceinline__ float sigm(float x) { return 1.0f / (1.0f + expf(-x)); }

// ---------------------------------------------------------------- init S
__global__ __launch_bounds__(256) void k_init(float* __restrict__ S,
                                              const float* __restrict__ h0,
                                              const float* __restrict__ z0) {
  int idx = blockIdx.x * 256 + threadIdx.x;   // over 16*1024*64 = 1,048,576
  int c = idx & 63;
  S[idx] = (idx < (8192 * 64)) ? h0[c] : z0[c];
}

// ---------------------------------------------------------------- A2 = A @ A (per batch)
__global__ __launch_bounds__(256) void k_a2(const float* __restrict__ A, float* __restrict__ A2) {
  const int b = blockIdx.z;
  const int m0 = blockIdx.y * 128, n0 = blockIdx.x * 128;
  const float* Ab = A + ((size_t)b << 20);
  __shared__ float As[8][136];   // [k][m], stride 136 -> f4-aligned rows, bank-safe
  __shared__ float Bs[8][136];   // [k][n]
  const int tx = threadIdx.x & 15, ty = threadIdx.x >> 4;
  float acc[8][8];
#pragma unroll
  for (int m = 0; m < 8; ++m)
#pragma unroll
    for (int n = 0; n < 8; ++n) acc[m][n] = 0.0f;

  for (int k0 = 0; k0 < 1024; k0 += 8) {
    int mm = threadIdx.x >> 1, k4 = (threadIdx.x & 1) * 4;
    float4 va = *(const float4*)&Ab[(size_t)(m0 + mm) * 1024 + k0 + k4];
    As[k4 + 0][mm] = va.x; As[k4 + 1][mm] = va.y; As[k4 + 2][mm] = va.z; As[k4 + 3][mm] = va.w;
    int kk = threadIdx.x >> 5, nn = (threadIdx.x & 31) * 4;
    float4 vb = *(const float4*)&Ab[(size_t)(k0 + kk) * 1024 + n0 + nn];
    *(float4*)&Bs[kk][nn] = vb;
    __syncthreads();
#pragma unroll
    for (int k = 0; k < 8; ++k) {
      float a[8], bb[8];
      *(float4*)&a[0] = *(float4*)&As[k][ty * 8];
      *(float4*)&a[4] = *(float4*)&As[k][ty * 8 + 4];
      *(float4*)&bb[0] = *(float4*)&Bs[k][tx * 8];
      *(float4*)&bb[4] = *(float4*)&Bs[k][tx * 8 + 4];
#pragma unroll
      for (int m = 0; m < 8; ++m)
#pragma unroll
        for (int n = 0; n < 8; ++n) acc[m][n] += a[m] * bb[n];
    }
    __syncthreads();
  }
  float* C = A2 + ((size_t)b << 20);
#pragma unroll
  for (int m = 0; m < 8; ++m) {
    size_t o = (size_t)(m0 + ty * 8 + m) * 1024 + n0 + tx * 8;
    *(float4*)&C[o]     = make_float4(acc[m][0], acc[m][1], acc[m][2], acc[m][3]);
    *(float4*)&C[o + 4] = make_float4(acc[m][4], acc[m][5], acc[m][6], acc[m][7]);
  }
}

// ---------------------------------------------------------------- stacked hop: HH = [A;A2] @ rhs
// MODE 0: rhs = S (D=64);  MODE 1: rhs = [x|S] (D=80);  MODE 2: rhs = [x|RH] (D=80)
template <int MODE>
__global__ __launch_bounds__(256) void k_hop(const float* __restrict__ A,
                                             const float* __restrict__ A2,
                                             const float* __restrict__ values,
                                             const float* __restrict__ masks,
                                             const float* __restrict__ Sv,
                                             const float* __restrict__ RHv,
                                             float* __restrict__ HH, int t) {
  constexpr int D = (MODE == 0) ? 64 : 80;
  constexpr int TN = D / 8;
  const int i = blockIdx.y, b = i & 7;
  const int m0 = blockIdx.x * 128;
  const float* Arow = (m0 < 1024) ? (A + ((size_t)b << 20) + (size_t)m0 * 1024)
                                  : (A2 + ((size_t)b << 20) + (size_t)(m0 - 1024) * 1024);
  __shared__ float As[128][33];   // pad 33 -> bank-conflict-free column reads
  __shared__ float Bs[32][D];
  const int cg = threadIdx.x & 7, rg = threadIdx.x >> 3;
  const float* Hrow = (MODE == 2) ? (RHv + ((size_t)i << 16)) : (Sv + ((size_t)i << 16));
  float acc[4][TN];
#pragma unroll
  for (int m = 0; m < 4; ++m)
#pragma unroll
    for (int n = 0; n < TN; ++n) acc[m][n] = 0.0f;

  for (int k0 = 0; k0 < 1024; k0 += 32) {
#pragma unroll
    for (int p = 0; p < 4; ++p) {
      int idx = threadIdx.x + p * 256;
      int c4 = (idx & 7) * 4, rr = idx >> 3;
      float4 v = *(const float4*)&Arow[(size_t)rr * 1024 + k0 + c4];
      As[rr][c4 + 0] = v.x; As[rr][c4 + 1] = v.y; As[rr][c4 + 2] = v.z; As[rr][c4 + 3] = v.w;
    }
    for (int idx = threadIdx.x; idx < 32 * D; idx += 256) {
      int rr, c;
      if (MODE == 0) { rr = idx >> 6; c = idx & 63; }
      else           { rr = idx / 80; c = idx - rr * 80; }
      int k = k0 + rr;
      float vv;
      if (MODE == 0) {
        vv = Hrow[(size_t)k * 64 + c];
      } else {
        if (c < 16) {
          size_t xo = ((((size_t)b * T_ + t) << 10) + k) * 16 + c;
          vv = values[xo] * masks[xo];
        } else {
          vv = Hrow[(size_t)k * 64 + (c - 16)];
        }
      }
      Bs[rr][c] = vv;
    }
    __syncthreads();
#pragma unroll 8
    for (int kk = 0; kk < 32; ++kk) {
      float a0 = As[rg * 4 + 0][kk], a1 = As[rg * 4 + 1][kk];
      float a2 = As[rg * 4 + 2][kk], a3 = As[rg * 4 + 3][kk];
#pragma unroll
      for (int n = 0; n < TN; ++n) {
        float x = Bs[kk][cg * TN + n];
        acc[0][n] += a0 * x; acc[1][n] += a1 * x;
        acc[2][n] += a2 * x; acc[3][n] += a3 * x;
      }
    }
    __syncthreads();
  }
#pragma unroll
  for (int m = 0; m < 4; ++m) {
    size_t o = ((size_t)i * 2048 + m0 + rg * 4 + m) * 80 + cg * TN;
#pragma unroll
    for (int n = 0; n < TN; ++n) HH[o + n] = acc[m][n];
  }
}

// ---------------------------------------------------------------- ODE tail
__global__ __launch_bounds__(256) void k_ode_tail(float* __restrict__ S,
    const float* __restrict__ HH,
    const float* __restrict__ vW0, const float* __restrict__ vb0,
    const float* __restrict__ vWout, const float* __restrict__ vbout,
    const float* __restrict__ gW0, const float* __restrict__ gb0,
    const float* __restrict__ gWout, const float* __restrict__ gbout) {
  __shared__ float Fs[32][200];   // feats 192, padded
  __shared__ float T1s[32][68];
  __shared__ float Wc[64][64];
  __shared__ float bias[64];
  const int rowbase = blockIdx.x * 32;
  const int i = rowbase >> 10, st = i >> 3;
  const float* W0 = st ? gW0 : vW0;
  const float* b0 = st ? gb0 : vb0;
  const float* Wo = st ? gWout : vWout;
  const float* bo = st ? gbout : vbout;
  const int r = threadIdx.x >> 3, q = threadIdx.x & 7;

  for (int idx = threadIdx.x; idx < 32 * 64; idx += 256) {
    int rr = idx >> 6, c = idx & 63;
    size_t g = (size_t)(rowbase + rr);
    int n = (int)(g & 1023);
    Fs[rr][c] = S[g * 64 + c];
    size_t hb = ((size_t)i * 2048 + n) * 80;
    Fs[rr][64 + c]  = HH[hb + c];
    Fs[rr][128 + c] = HH[hb + (size_t)1024 * 80 + c];
  }
  if (threadIdx.x < 64) bias[threadIdx.x] = b0[threadIdx.x];

  float acc[8];
#pragma unroll
  for (int j = 0; j < 8; ++j) acc[j] = 0.0f;
  for (int kc = 0; kc < 3; ++kc) {
    __syncthreads();
    for (int idx = threadIdx.x; idx < 1024; idx += 256)
      ((float4*)Wc)[idx] = ((const float4*)W0)[kc * 1024 + idx];
    __syncthreads();
#pragma unroll 8
    for (int k = 0; k < 64; ++k) {
      float f = Fs[r][kc * 64 + k];
      float4 w0 = *(float4*)&Wc[k][q * 8];
      float4 w1 = *(float4*)&Wc[k][q * 8 + 4];
      acc[0] += f * w0.x; acc[1] += f * w0.y; acc[2] += f * w0.z; acc[3] += f * w0.w;
      acc[4] += f * w1.x; acc[5] += f * w1.y; acc[6] += f * w1.z; acc[7] += f * w1.w;
    }
  }
#pragma unroll
  for (int j = 0; j < 8; ++j) T1s[r][q * 8 + j] = tanhf(acc[j] + bias[q * 8 + j]);
  __syncthreads();
  if (threadIdx.x < 64) bias[threadIdx.x] = bo[threadIdx.x];
  for (int idx = threadIdx.x; idx < 1024; idx += 256)
    ((float4*)Wc)[idx] = ((const float4*)Wo)[idx];
  __syncthreads();
  float a2[8];
#pragma unroll
  for (int j = 0; j < 8; ++j) a2[j] = 0.0f;
#pragma unroll 8
  for (int k = 0; k < 64; ++k) {
    float f = T1s[r][k];
    float4 w0 = *(float4*)&Wc[k][q * 8];
    float4 w1 = *(float4*)&Wc[k][q * 8 + 4];
    a2[0] += f * w0.x; a2[1] += f * w0.y; a2[2] += f * w0.z; a2[3] += f * w0.w;
    a2[4] += f * w1.x; a2[5] += f * w1.y; a2[6] += f * w1.z; a2[7] += f * w1.w;
  }
  size_t g = (size_t)(rowbase + r);
#pragma unroll
  for (int j = 0; j < 8; ++j) {
    size_t o = g * 64 + q * 8 + j;
    S[o] += 0.025f * tanhf(a2[j] + bias[q * 8 + j]);
  }
}

// ---------------------------------------------------------------- gate tail
__global__ __launch_bounds__(256) void k_gate_tail(const float* __restrict__ values,
    const float* __restrict__ masks, const float* __restrict__ S,
    const float* __restrict__ HH, float* __restrict__ RH, float* __restrict__ U,
    const float* __restrict__ vWg, const float* __restrict__ vbg,
    const float* __restrict__ gWg, const float* __restrict__ gbg, int t) {
  __shared__ float Fs[32][248];   // feats 240, padded
  __shared__ float Wc[48][128];
  __shared__ float bgs[128];
  const int rowbase = blockIdx.x * 32;
  const int i = rowbase >> 10, st = i >> 3, b = i & 7;
  const float* Wg = st ? gWg : vWg;
  const float* bg = st ? gbg : vbg;
  const int r = threadIdx.x >> 3, q = threadIdx.x & 7;

  for (int idx = threadIdx.x; idx < 32 * 80; idx += 256) {
    int rr = idx / 80, c = idx - rr * 80;
    size_t g = (size_t)(rowbase + rr);
    int n = (int)(g & 1023);
    float xh;
    if (c < 16) {
      size_t xo = ((((size_t)b * T_ + t) << 10) + n) * 16 + c;
      xh = values[xo] * masks[xo];
    } else {
      xh = S[g * 64 + (c - 16)];
    }
    Fs[rr][c] = xh;
    size_t hb = ((size_t)i * 2048 + n) * 80;
    Fs[rr][80 + c]  = HH[hb + c];
    Fs[rr][160 + c] = HH[hb + (size_t)1024 * 80 + c];
  }
  if (threadIdx.x < 128) bgs[threadIdx.x] = bg[threadIdx.x];

  float acc[16];
#pragma unroll
  for (int j = 0; j < 16; ++j) acc[j] = 0.0f;
  for (int kc = 0; kc < 5; ++kc) {
    __syncthreads();
    for (int idx = threadIdx.x; idx < 1536; idx += 256)
      ((float4*)Wc)[idx] = ((const float4*)Wg)[kc * 1536 + idx];
    __syncthreads();
#pragma unroll 8
    for (int k = 0; k < 48; ++k) {
      float f = Fs[r][kc * 48 + k];
      float4 w0 = *(float4*)&Wc[k][q * 16];
      float4 w1 = *(float4*)&Wc[k][q * 16 + 4];
      float4 w2 = *(float4*)&Wc[k][q * 16 + 8];
      float4 w3 = *(float4*)&Wc[k][q * 16 + 12];
      acc[0]  += f * w0.x; acc[1]  += f * w0.y; acc[2]  += f * w0.z; acc[3]  += f * w0.w;
      acc[4]  += f * w1.x; acc[5]  += f * w1.y; acc[6]  += f * w1.z; acc[7]  += f * w1.w;
      acc[8]  += f * w2.x; acc[9]  += f * w2.y; acc[10] += f * w2.z; acc[11] += f * w2.w;
      acc[12] += f * w3.x; acc[13] += f * w3.y; acc[14] += f * w3.z; acc[15] += f * w3.w;
    }
  }
  size_t g = (size_t)(rowbase + r);
  if (q < 4) {  // reset-gate half -> RH = r*h  (h = feats[16..79])
#pragma unroll
    for (int jj = 0; jj < 16; ++jj) {
      int c = q * 16 + jj;
      float rr_ = sigm(acc[jj] + bgs[c]);
      RH[g * 64 + c] = rr_ * Fs[r][16 + c];
    }
  } else {      // update-gate half -> U
#pragma unroll
    for (int jj = 0; jj < 16; ++jj) {
      int c = (q - 4) * 16 + jj;
      U[g * 64 + c] = sigm(acc[jj] + bgs[64 + c]);
    }
  }
}

// ---------------------------------------------------------------- candidate tail + state update
__global__ __launch_bounds__(256) void k_cand_tail(const float* __restrict__ values,
    const float* __restrict__ masks, float* __restrict__ S,
    const float* __restrict__ HH, const float* __restrict__ RH, const float* __restrict__ U,
    const float* __restrict__ vWc, const float* __restrict__ vbc,
    const float* __restrict__ gWc, const float* __restrict__ gbc, int t) {
  __shared__ float Fs[32][248];
  __shared__ float Wc[48][64];
  __shared__ float bcs[64];
  __shared__ float Ms[32];
  const int rowbase = blockIdx.x * 32;
  const int i = rowbase >> 10, st = i >> 3, b = i & 7;
  const float* Wcc = st ? gWc : vWc;
  const float* bc = st ? gbc : vbc;
  const int r = threadIdx.x >> 3, q = threadIdx.x & 7;

  for (int idx = threadIdx.x; idx < 32 * 80; idx += 256) {
    int rr = idx / 80, c = idx - rr * 80;
    size_t g = (size_t)(rowbase + rr);
    int n = (int)(g & 1023);
    float xh;
    if (c < 16) {
      size_t xo = ((((size_t)b * T_ + t) << 10) + n) * 16 + c;
      xh = values[xo] * masks[xo];
    } else {
      xh = RH[g * 64 + (c - 16)];
    }
    Fs[rr][c] = xh;
    size_t hb = ((size_t)i * 2048 + n) * 80;
    Fs[rr][80 + c]  = HH[hb + c];
    Fs[rr][160 + c] = HH[hb + (size_t)1024 * 80 + c];
  }
  if (threadIdx.x < 64) bcs[threadIdx.x] = bc[threadIdx.x];
  if (threadIdx.x < 32) {
    int n = (rowbase + threadIdx.x) & 1023;
    size_t xo = ((((size_t)b * T_ + t) << 10) + n) * 16;
    float s = 0.0f;
    for (int d = 0; d < 16; ++d) s += fabsf(masks[xo + d]);
    Ms[threadIdx.x] = (s > 1e-4f) ? 1.0f : 0.0f;
  }

  float acc[8];
#pragma unroll
  for (int j = 0; j < 8; ++j) acc[j] = 0.0f;
  for (int kc = 0; kc < 5; ++kc) {
    __syncthreads();
    for (int idx = threadIdx.x; idx < 768; idx += 256)
      ((float4*)Wc)[idx] = ((const float4*)Wcc)[kc * 768 + idx];
    __syncthreads();
#pragma unroll 8
    for (int k = 0; k < 48; ++k) {
      float f = Fs[r][kc * 48 + k];
      float4 w0 = *(float4*)&Wc[k][q * 8];
      float4 w1 = *(float4*)&Wc[k][q * 8 + 4];
      acc[0] += f * w0.x; acc[1] += f * w0.y; acc[2] += f * w0.z; acc[3] += f * w0.w;
      acc[4] += f * w1.x; acc[5] += f * w1.y; acc[6] += f * w1.z; acc[7] += f * w1.w;
    }
  }
  size_t g = (size_t)(rowbase + r);
  float m = Ms[r];
#pragma unroll
  for (int jj = 0; jj < 8; ++jj) {
    int c = q * 8 + jj;
    float cc = tanhf(acc[jj] + bcs[c]);
    float h1 = S[g * 64 + c];
    float u  = U[g * 64 + c];
    float h2 = u * h1 + (1.0f - u) * cc;
    S[g * 64 + c] = h1 * (1.0f - m) + h2 * m;
  }
}

// ---------------------------------------------------------------- output tail (gate chain + projection)
__global__ __launch_bounds__(256) void k_out(const float* __restrict__ S,
    const float* __restrict__ Wz1, const float* __restrict__ bz1,
    const float* __restrict__ Wz2, const float* __restrict__ bz2,
    const float* __restrict__ Wz3, const float* __restrict__ bz3,
    const float* __restrict__ Wo, const float* __restrict__ bo,
    float* __restrict__ out, int t) {
  __shared__ float Zs[32][68];
  __shared__ float T1s[32][68];
  __shared__ float Hs[32][68];
  __shared__ float Wc[64][64];
  __shared__ float bias[64];
  const int rowbase = blockIdx.x * 32;   // rows over (b,n): 8192
  const int r = threadIdx.x >> 3, q = threadIdx.x & 7;

  for (int idx = threadIdx.x; idx < 2048; idx += 256) {
    int rr = idx >> 6, c = idx & 63;
    size_t g = (size_t)(rowbase + rr);
    Zs[rr][c] = S[(size_t)524288 + g * 64 + c];   // zv_pre
    Hs[rr][c] = S[g * 64 + c];                    // hv_pre
  }

#define LAYER(SRC, DST, WPTR, BPTR, ACT)                                            \
  __syncthreads();                                                                  \
  for (int idx = threadIdx.x; idx < 1024; idx += 256)                               \
    ((float4*)Wc)[idx] = ((const float4*)(WPTR))[idx];                              \
  if (threadIdx.x < 64) bias[threadIdx.x] = (BPTR)[threadIdx.x];                    \
  __syncthreads();                                                                  \
  {                                                                                 \
    float ac[8] = {0, 0, 0, 0, 0, 0, 0, 0};                                         \
    _Pragma("unroll 8") for (int k = 0; k < 64; ++k) {                              \
      float f = SRC[r][k];                                                          \
      float4 w0 = *(float4*)&Wc[k][q * 8];                                          \
      float4 w1 = *(float4*)&Wc[k][q * 8 + 4];                                      \
      ac[0] += f * w0.x; ac[1] += f * w0.y; ac[2] += f * w0.z; ac[3] += f * w0.w;   \
      ac[4] += f * w1.x; ac[5] += f * w1.y; ac[6] += f * w1.z; ac[7] += f * w1.w;   \
    }                                                                               \
    _Pragma("unroll") for (int j = 0; j < 8; ++j)                                   \
        DST[r][q * 8 + j] = ACT(ac[j] + bias[q * 8 + j]);                           \
  }

  LAYER(Zs, T1s, Wz1, bz1, tanhf)
  LAYER(T1s, Zs, Wz2, bz2, tanhf)
  LAYER(Zs, T1s, Wz3, bz3, sigm)
#undef LAYER

  __syncthreads();
  for (int idx = threadIdx.x; idx < 256; idx += 256)
    ((float4*)Wc)[idx] = ((const float4*)Wo)[idx];   // Wo 64x16 flat
  if (threadIdx.x < 16) bias[threadIdx.x] = bo[threadIdx.x];
  __syncthreads();

  const float* WcF = &Wc[0][0];
  float a0 = 0.0f, a1 = 0.0f;
#pragma unroll 8
  for (int k = 0; k < 64; ++k) {
    float f = Hs[r][k] * T1s[r][k];
    a0 += f * WcF[k * 16 + q * 2];
    a1 += f * WcF[k * 16 + q * 2 + 1];
  }
  size_t g = (size_t)(rowbase + r);
  int b = (int)(g >> 10), n = (int)(g & 1023);
  size_t o = (((size_t)b * 39 + (t - 1)) * 1024 + n) * 16 + q * 2;
  out[o]     = a0 + bias[q * 2];
  out[o + 1] = a1 + bias[q * 2 + 1];
}

// ---------------------------------------------------------------- launch
extern "C" void kernel_launch(void* const* d_in, const int* in_sizes, int n_in,
                              void* d_out, int out_size, void* d_ws, size_t ws_size,
                              hipStream_t stream) {
  const float* values = (const float*)d_in[0];
  const float* masks  = (const float*)d_in[1];
  const float* A      = (const float*)d_in[2];
  const float* h0     = (const float*)d_in[3];
  const float* z0     = (const float*)d_in[4];
  const float* gV_Wg  = (const float*)d_in[5];
  const float* gV_bg  = (const float*)d_in[6];
  const float* gV_Wc  = (const float*)d_in[7];
  const float* gV_bc  = (const float*)d_in[8];
  const float* gG_Wg  = (const float*)d_in[9];
  const float* gG_bg  = (const float*)d_in[10];
  const float* gG_Wc  = (const float*)d_in[11];
  const float* gG_bc  = (const float*)d_in[12];
  const float* oV_W0  = (const float*)d_in[13];
  const float* oV_b0  = (const float*)d_in[14];
  const float* oV_Wout = (const float*)d_in[15];
  const float* oV_bout = (const float*)d_in[16];
  const float* oG_W0  = (const float*)d_in[17];
  const float* oG_b0  = (const float*)d_in[18];
  const float* oG_Wout = (const float*)d_in[19];
  const float* oG_bout = (const float*)d_in[20];
  const float* Wz1 = (const float*)d_in[21];
  const float* bz1 = (const float*)d_in[22];
  const float* Wz2 = (const float*)d_in[23];
  const float* bz2 = (const float*)d_in[24];
  const float* Wz3 = (const float*)d_in[25];
  const float* bz3 = (const float*)d_in[26];
  const float* Wo  = (const float*)d_in[27];
  const float* bo  = (const float*)d_in[28];
  float* out = (float*)d_out;

  if (ws_size < (size_t)14155776 * 4) return;
  float* ws = (float*)d_ws;
  float* S  = ws;
  float* HH = ws + 1048576;
  float* RH = ws + 3670016;
  float* U  = ws + 4718592;
  float* A2 = ws + 5767168;

  k_init<<<4096, 256, 0, stream>>>(S, h0, z0);
  k_a2<<<dim3(8, 8, 8), 256, 0, stream>>>(A, A2);

  for (int t = 0; t < T_; ++t) {
    for (int e = 0; e < 2; ++e) {
      k_hop<0><<<dim3(16, 16), 256, 0, stream>>>(A, A2, values, masks, S, nullptr, HH, t);
      k_ode_tail<<<512, 256, 0, stream>>>(S, HH, oV_W0, oV_b0, oV_Wout, oV_bout,
                                          oG_W0, oG_b0, oG_Wout, oG_bout);
    }
    if (t >= 1)
      k_out<<<256, 256, 0, stream>>>(S, Wz1, bz1, Wz2, bz2, Wz3, bz3, Wo, bo, out, t);
    k_hop<1><<<dim3(16, 16), 256, 0, stream>>>(A, A2, values, masks, S, nullptr, HH, t);
    k_gate_tail<<<512, 256, 0, stream>>>(values, masks, S, HH, RH, U,
                                         gV_Wg, gV_bg, gG_Wg, gG_bg, t);
    k_hop<2><<<dim3(16, 16), 256, 0, stream>>>(A, A2, values, masks, S, RH, HH, t);
    k_cand_tail<<<512, 256, 0, stream>>>(values, masks, S, HH, RH, U,
                                         gV_Wc, gV_bc, gG_Wc, gG_bc, t);
  }
}

// Round 3
// 9469.717 us; speedup vs baseline: 3.5901x; 3.5901x over previous
//
#include <hip/hip_runtime.h>
#include <math.h>

// GRU-ODE / DCGRU on dense graph. B=8, T=40, N=1024, DIN=16, DR=64, DH=64, K=3.
// Round 3: bf16 MFMA for all A-hops (state-batched), fp32 accum + fp32 HH staging.
//
// ws layout (bytes):
//   S    f32 [16][1024][64]  @ 0
//   RH   f32 [16][1024][64]  @ 4194304
//   U    f32 [16][1024][64]  @ 8388608
//   HHS  f32 [16][2048][64]  @ 12582912
//   HHX  f32 [8][2048][16]   @ 20971520
//   SB   bf16 [16][64][1024] @ 22020096   (col-major state mirror)
//   RHB  bf16 [16][64][1024] @ 24117248
//   XB   bf16 [8][40][16][1024] @ 26214400
//   AS   bf16 [8][2048][1024]   @ 36700160  (rows 0..1023 = A, 1024.. = A2)
//   total 70254592 B

#define T_ 40

typedef __attribute__((ext_vector_type(8))) short short8;
typedef __attribute__((ext_vector_type(4))) float f32x4;

__device__ __forceinline__ float sigm(float x) { return 1.0f / (1.0f + expf(-x)); }

__device__ __forceinline__ unsigned short bfrnd(float x) {
  union { float f; unsigned int u; } v; v.f = x;
  unsigned int u = v.u + 0x7fffu + ((v.u >> 16) & 1u);
  return (unsigned short)(u >> 16);
}
__device__ __forceinline__ unsigned int pk2(float a, float b) {
  return (unsigned int)bfrnd(a) | ((unsigned int)bfrnd(b) << 16);
}

// ---------------------------------------------------------------- init S + SB mirror
__global__ __launch_bounds__(256) void k_init(float* __restrict__ S, unsigned short* __restrict__ SB,
                                              const float* __restrict__ h0,
                                              const float* __restrict__ z0) {
  int idx = blockIdx.x * 256 + threadIdx.x;   // over 16*1024*64
  int c = idx & 63;
  float v = (idx < (8192 * 64)) ? h0[c] : z0[c];
  S[idx] = v;
  // SB flat: [(i*64+c)*1024+n]; map idx -> i=idx>>16, cc=(idx>>10)&63
  int cc = (idx >> 10) & 63;
  float v2 = ((idx >> 16) < 8) ? h0[cc] : z0[cc];
  SB[idx] = bfrnd(v2);
}

// ---------------------------------------------------------------- A rows -> bf16 AS
__global__ __launch_bounds__(256) void k_asA(const float* __restrict__ A, unsigned short* __restrict__ AS) {
  size_t j = ((size_t)blockIdx.x * 256 + threadIdx.x) * 8;   // over 8*1024*1024 elems
  if (j >= (size_t)8 * 1024 * 1024) return;
  int b = (int)(j >> 20);
  size_t rem = j & 1048575;
  int r = (int)(rem >> 10), k = (int)(rem & 1023);
  const float* src = A + ((size_t)b << 20) + (size_t)r * 1024 + k;
  float4 v0 = *(const float4*)src;
  float4 v1 = *(const float4*)(src + 4);
  uint4 o;
  o.x = pk2(v0.x, v0.y); o.y = pk2(v0.z, v0.w);
  o.z = pk2(v1.x, v1.y); o.w = pk2(v1.z, v1.w);
  *(uint4*)(AS + ((size_t)b * 2048 + r) * 1024 + k) = o;
}

// ---------------------------------------------------------------- XB: col-major bf16 x (values*masks)
__global__ __launch_bounds__(256) void k_xb(const float* __restrict__ values,
                                            const float* __restrict__ masks,
                                            unsigned short* __restrict__ XB) {
  const int bt = blockIdx.x;          // 0..319 = b*40+t
  const int n0 = blockIdx.y * 256;
  __shared__ float Ls[256][17];
  const int tid = threadIdx.x;
  size_t base = ((size_t)bt * 1024 + n0 + tid) * 16;
#pragma unroll
  for (int c4 = 0; c4 < 4; ++c4) {
    float4 v = *(const float4*)&values[base + c4 * 4];
    float4 m = *(const float4*)&masks[base + c4 * 4];
    Ls[tid][c4 * 4 + 0] = v.x * m.x; Ls[tid][c4 * 4 + 1] = v.y * m.y;
    Ls[tid][c4 * 4 + 2] = v.z * m.z; Ls[tid][c4 * 4 + 3] = v.w * m.w;
  }
  __syncthreads();
  const int c = tid >> 4, seg = tid & 15;   // c 0..15, seg 0..15 (n-run of 16)
  uint4 o1, o2;
  o1.x = pk2(Ls[seg * 16 + 0][c], Ls[seg * 16 + 1][c]);
  o1.y = pk2(Ls[seg * 16 + 2][c], Ls[seg * 16 + 3][c]);
  o1.z = pk2(Ls[seg * 16 + 4][c], Ls[seg * 16 + 5][c]);
  o1.w = pk2(Ls[seg * 16 + 6][c], Ls[seg * 16 + 7][c]);
  o2.x = pk2(Ls[seg * 16 + 8][c], Ls[seg * 16 + 9][c]);
  o2.y = pk2(Ls[seg * 16 + 10][c], Ls[seg * 16 + 11][c]);
  o2.z = pk2(Ls[seg * 16 + 12][c], Ls[seg * 16 + 13][c]);
  o2.w = pk2(Ls[seg * 16 + 14][c], Ls[seg * 16 + 15][c]);
  unsigned short* dst = XB + ((size_t)bt * 16 + c) * 1024 + n0 + seg * 16;
  *(uint4*)dst = o1;
  *(uint4*)(dst + 8) = o2;
}

// ---------------------------------------------------------------- A2 = A @ A (fp32 compute, bf16 store into AS)
__global__ __launch_bounds__(256) void k_a2(const float* __restrict__ A, unsigned short* __restrict__ AS) {
  const int b = blockIdx.z;
  const int m0 = blockIdx.y * 128, n0 = blockIdx.x * 128;
  const float* Ab = A + ((size_t)b << 20);
  __shared__ float As[8][136];
  __shared__ float Bs[8][136];
  const int tx = threadIdx.x & 15, ty = threadIdx.x >> 4;
  float acc[8][8];
#pragma unroll
  for (int m = 0; m < 8; ++m)
#pragma unroll
    for (int n = 0; n < 8; ++n) acc[m][n] = 0.0f;

  for (int k0 = 0; k0 < 1024; k0 += 8) {
    int mm = threadIdx.x >> 1, k4 = (threadIdx.x & 1) * 4;
    float4 va = *(const float4*)&Ab[(size_t)(m0 + mm) * 1024 + k0 + k4];
    As[k4 + 0][mm] = va.x; As[k4 + 1][mm] = va.y; As[k4 + 2][mm] = va.z; As[k4 + 3][mm] = va.w;
    int kk = threadIdx.x >> 5, nn = (threadIdx.x & 31) * 4;
    float4 vb = *(const float4*)&Ab[(size_t)(k0 + kk) * 1024 + n0 + nn];
    *(float4*)&Bs[kk][nn] = vb;
    __syncthreads();
#pragma unroll
    for (int k = 0; k < 8; ++k) {
      float a[8], bb[8];
      *(float4*)&a[0] = *(float4*)&As[k][ty * 8];
      *(float4*)&a[4] = *(float4*)&As[k][ty * 8 + 4];
      *(float4*)&bb[0] = *(float4*)&Bs[k][tx * 8];
      *(float4*)&bb[4] = *(float4*)&Bs[k][tx * 8 + 4];
#pragma unroll
      for (int m = 0; m < 8; ++m)
#pragma unroll
        for (int n = 0; n < 8; ++n) acc[m][n] += a[m] * bb[n];
    }
    __syncthreads();
  }
#pragma unroll
  for (int m = 0; m < 8; ++m) {
    unsigned short* C = AS + ((size_t)b * 2048 + 1024 + m0 + ty * 8 + m) * 1024 + n0 + tx * 8;
    uint4 o;
    o.x = pk2(acc[m][0], acc[m][1]); o.y = pk2(acc[m][2], acc[m][3]);
    o.z = pk2(acc[m][4], acc[m][5]); o.w = pk2(acc[m][6], acc[m][7]);
    *(uint4*)C = o;
  }
}

// ---------------------------------------------------------------- MFMA hop: HH = [A;A2]_b @ rhs
// MODE 0: rhs=[h|z] N=128 (NT=8);  MODE 1: rhs=[x|h|z] N=144 (NT=9);  MODE 2: rhs=[rh|rz] N=128 (NT=8)
template <int NT, int MODE>
__global__ __launch_bounds__(256) void k_hop_mfma(
    const unsigned short* __restrict__ AS,
    const unsigned short* __restrict__ XB,
    const unsigned short* __restrict__ SB,
    const unsigned short* __restrict__ RHB,
    float* __restrict__ HHS, float* __restrict__ HHX, int t) {
  __shared__ __align__(16) unsigned short lds_a[2][4][512];
  __shared__ __align__(16) unsigned short lds_b[2][NT][512];
  const int tid = threadIdx.x;
  const int w = tid >> 6, l = tid & 63;
  const int b = blockIdx.y;
  const int m0 = blockIdx.x * 64;
  const int lr = l & 15, lk = l >> 4;

  // per-lane global src for A row-tile w (frag-linear: lds slot l <- A[m0+w*16+lr][k0+lk*8 ..+7])
  const unsigned short* agp = AS + ((size_t)b * 2048 + m0 + w * 16 + lr) * 1024 + lk * 8;

  const int bstart = (NT == 9) ? ((w == 0) ? 0 : (1 + 2 * w)) : (2 * w);
  const int bcnt   = (NT == 9) ? ((w == 0) ? 3 : 2) : 2;

  // B sources (col-major [c][k] global), per-lane row = tile-col lr
  auto bsrc = [&](int ct) -> const unsigned short* {
    if (MODE == 1) {
      if (ct == 0)      return XB + (((size_t)(b * T_ + t)) * 16 + lr) * 1024;
      else if (ct < 5)  return SB + ((size_t)b * 64 + (size_t)(ct - 1) * 16 + lr) * 1024;
      else              return SB + ((size_t)(8 + b) * 64 + (size_t)(ct - 5) * 16 + lr) * 1024;
    } else {
      const unsigned short* base = (MODE == 2) ? RHB : SB;
      if (ct < 4) return base + ((size_t)b * 64 + (size_t)ct * 16 + lr) * 1024;
      else        return base + ((size_t)(8 + b) * 64 + (size_t)(ct - 4) * 16 + lr) * 1024;
    }
  };

  f32x4 acc[4][3];
#pragma unroll
  for (int rt = 0; rt < 4; ++rt)
#pragma unroll
    for (int ci = 0; ci < 3; ++ci) acc[rt][ci] = (f32x4){0.f, 0.f, 0.f, 0.f};

#define STAGE(BUF, K0)                                                                         \
  {                                                                                            \
    __builtin_amdgcn_global_load_lds(                                                          \
        (const __attribute__((address_space(1))) void*)(agp + (K0)),                           \
        (__attribute__((address_space(3))) void*)&lds_a[BUF][w][0], 16, 0, 0);                 \
    for (int ct = w; ct < NT; ct += 4)                                                         \
      __builtin_amdgcn_global_load_lds(                                                        \
          (const __attribute__((address_space(1))) void*)(bsrc(ct) + (K0) + lk * 8),           \
          (__attribute__((address_space(3))) void*)&lds_b[BUF][ct][0], 16, 0, 0);              \
  }

  int cur = 0;
  STAGE(0, 0)
  __syncthreads();
  for (int step = 0; step < 32; ++step) {
    const int nxt = cur ^ 1;
    if (step < 31) STAGE(nxt, (step + 1) * 32)
    short8 af[4];
#pragma unroll
    for (int rt = 0; rt < 4; ++rt)
      af[rt] = *(const short8*)&lds_a[cur][rt][l * 8];
#pragma unroll
    for (int ci = 0; ci < 3; ++ci) {
      if (ci < bcnt) {
        short8 bf = *(const short8*)&lds_b[cur][bstart + ci][l * 8];
#pragma unroll
        for (int rt = 0; rt < 4; ++rt)
          acc[rt][ci] = __builtin_amdgcn_mfma_f32_16x16x32_bf16(af[rt], bf, acc[rt][ci], 0, 0, 0);
      }
    }
    __syncthreads();
    cur = nxt;
  }
#undef STAGE

  // epilogue: C/D layout col=lane&15, row=(lane>>4)*4+reg  [m89]
#pragma unroll
  for (int ci = 0; ci < 3; ++ci) {
    if (ci < bcnt) {
      const int ct = bstart + ci;
      float* dst; int ldc, csub;
      if (MODE == 1) {
        if (ct == 0)     { dst = HHX + (size_t)b * 2048 * 16;      ldc = 16; csub = lr; }
        else if (ct < 5) { dst = HHS + (size_t)b * 2048 * 64;      ldc = 64; csub = (ct - 1) * 16 + lr; }
        else             { dst = HHS + (size_t)(8 + b) * 2048 * 64; ldc = 64; csub = (ct - 5) * 16 + lr; }
      } else {
        if (ct < 4) { dst = HHS + (size_t)b * 2048 * 64;       ldc = 64; csub = ct * 16 + lr; }
        else        { dst = HHS + (size_t)(8 + b) * 2048 * 64; ldc = 64; csub = (ct - 4) * 16 + lr; }
      }
#pragma unroll
      for (int rt = 0; rt < 4; ++rt) {
        const int rbase = m0 + rt * 16 + lk * 4;
#pragma unroll
        for (int j = 0; j < 4; ++j)
          dst[(size_t)(rbase + j) * ldc + csub] = acc[rt][ci][j];
      }
    }
  }
}

// ---------------------------------------------------------------- ODE tail (+ SB mirror)
__global__ __launch_bounds__(256) void k_ode_tail(float* __restrict__ S, unsigned short* __restrict__ SB,
    const float* __restrict__ HHS,
    const float* __restrict__ vW0, const float* __restrict__ vb0,
    const float* __restrict__ vWout, const float* __restrict__ vbout,
    const float* __restrict__ gW0, const float* __restrict__ gb0,
    const float* __restrict__ gWout, const float* __restrict__ gbout) {
  __shared__ float Fs[32][200];
  __shared__ float T1s[32][68];
  __shared__ float Wc[64][64];
  __shared__ float bias[64];
  __shared__ float Ts[64][33];
  const int rowbase = blockIdx.x * 32;
  const int i = rowbase >> 10, st = i >> 3;
  const float* W0 = st ? gW0 : vW0;
  const float* b0 = st ? gb0 : vb0;
  const float* Wo = st ? gWout : vWout;
  const float* bo = st ? gbout : vbout;
  const int r = threadIdx.x >> 3, q = threadIdx.x & 7;

  for (int idx = threadIdx.x; idx < 32 * 64; idx += 256) {
    int rr = idx >> 6, c = idx & 63;
    size_t g = (size_t)(rowbase + rr);
    int n = (int)(g & 1023);
    Fs[rr][c] = S[g * 64 + c];
    Fs[rr][64 + c]  = HHS[((size_t)i * 2048 + n) * 64 + c];
    Fs[rr][128 + c] = HHS[((size_t)i * 2048 + 1024 + n) * 64 + c];
  }
  if (threadIdx.x < 64) bias[threadIdx.x] = b0[threadIdx.x];

  float acc[8];
#pragma unroll
  for (int j = 0; j < 8; ++j) acc[j] = 0.0f;
  for (int kc = 0; kc < 3; ++kc) {
    __syncthreads();
    for (int idx = threadIdx.x; idx < 1024; idx += 256)
      ((float4*)Wc)[idx] = ((const float4*)W0)[kc * 1024 + idx];
    __syncthreads();
#pragma unroll 8
    for (int k = 0; k < 64; ++k) {
      float f = Fs[r][kc * 64 + k];
      float4 w0 = *(float4*)&Wc[k][q * 8];
      float4 w1 = *(float4*)&Wc[k][q * 8 + 4];
      acc[0] += f * w0.x; acc[1] += f * w0.y; acc[2] += f * w0.z; acc[3] += f * w0.w;
      acc[4] += f * w1.x; acc[5] += f * w1.y; acc[6] += f * w1.z; acc[7] += f * w1.w;
    }
  }
#pragma unroll
  for (int j = 0; j < 8; ++j) T1s[r][q * 8 + j] = tanhf(acc[j] + bias[q * 8 + j]);
  __syncthreads();
  if (threadIdx.x < 64) bias[threadIdx.x] = bo[threadIdx.x];
  for (int idx = threadIdx.x; idx < 1024; idx += 256)
    ((float4*)Wc)[idx] = ((const float4*)Wo)[idx];
  __syncthreads();
  float a2[8];
#pragma unroll
  for (int j = 0; j < 8; ++j) a2[j] = 0.0f;
#pragma unroll 8
  for (int k = 0; k < 64; ++k) {
    float f = T1s[r][k];
    float4 w0 = *(float4*)&Wc[k][q * 8];
    float4 w1 = *(float4*)&Wc[k][q * 8 + 4];
    a2[0] += f * w0.x; a2[1] += f * w0.y; a2[2] += f * w0.z; a2[3] += f * w0.w;
    a2[4] += f * w1.x; a2[5] += f * w1.y; a2[6] += f * w1.z; a2[7] += f * w1.w;
  }
  size_t g = (size_t)(rowbase + r);
#pragma unroll
  for (int j = 0; j < 8; ++j) {
    size_t o = g * 64 + q * 8 + j;
    float ns = S[o] + 0.025f * tanhf(a2[j] + bias[q * 8 + j]);
    S[o] = ns;
    Ts[q * 8 + j][r] = ns;
  }
  __syncthreads();
  // transpose-out SB mirror: thread -> (c, p): SB[i][c][n0 + p*8 .. +7]
  {
    const int c = threadIdx.x >> 2, p = threadIdx.x & 3;
    const int n0 = rowbase & 1023;
    uint4 o;
    o.x = pk2(Ts[c][p * 8 + 0], Ts[c][p * 8 + 1]);
    o.y = pk2(Ts[c][p * 8 + 2], Ts[c][p * 8 + 3]);
    o.z = pk2(Ts[c][p * 8 + 4], Ts[c][p * 8 + 5]);
    o.w = pk2(Ts[c][p * 8 + 6], Ts[c][p * 8 + 7]);
    *(uint4*)(SB + ((size_t)i * 64 + c) * 1024 + n0 + p * 8) = o;
  }
}

// ---------------------------------------------------------------- gate tail (+ RH fp32 + RHB mirror)
__global__ __launch_bounds__(256) void k_gate_tail(const float* __restrict__ values,
    const float* __restrict__ masks, const float* __restrict__ S,
    const float* __restrict__ HHS, const float* __restrict__ HHX,
    float* __restrict__ RH, unsigned short* __restrict__ RHB, float* __restrict__ U,
    const float* __restrict__ vWg, const float* __restrict__ vbg,
    const float* __restrict__ gWg, const float* __restrict__ gbg, int t) {
  __shared__ float Fs[32][248];
  __shared__ float Wc[48][128];
  __shared__ float bgs[128];
  __shared__ float Ts[64][33];
  const int rowbase = blockIdx.x * 32;
  const int i = rowbase >> 10, st = i >> 3, b = i & 7;
  const float* Wg = st ? gWg : vWg;
  const float* bg = st ? gbg : vbg;
  const int r = threadIdx.x >> 3, q = threadIdx.x & 7;

  for (int idx = threadIdx.x; idx < 32 * 80; idx += 256) {
    int rr = idx / 80, c = idx - rr * 80;
    size_t g = (size_t)(rowbase + rr);
    int n = (int)(g & 1023);
    float xh, v1, v2;
    if (c < 16) {
      size_t xo = ((((size_t)b * T_ + t) << 10) + n) * 16 + c;
      xh = values[xo] * masks[xo];
      v1 = HHX[((size_t)b * 2048 + n) * 16 + c];
      v2 = HHX[((size_t)b * 2048 + 1024 + n) * 16 + c];
    } else {
      xh = S[g * 64 + (c - 16)];
      v1 = HHS[((size_t)i * 2048 + n) * 64 + (c - 16)];
      v2 = HHS[((size_t)i * 2048 + 1024 + n) * 64 + (c - 16)];
    }
    Fs[rr][c] = xh;
    Fs[rr][80 + c]  = v1;
    Fs[rr][160 + c] = v2;
  }
  if (threadIdx.x < 128) bgs[threadIdx.x] = bg[threadIdx.x];

  float acc[16];
#pragma unroll
  for (int j = 0; j < 16; ++j) acc[j] = 0.0f;
  for (int kc = 0; kc < 5; ++kc) {
    __syncthreads();
    for (int idx = threadIdx.x; idx < 1536; idx += 256)
      ((float4*)Wc)[idx] = ((const float4*)Wg)[kc * 1536 + idx];
    __syncthreads();
#pragma unroll 8
    for (int k = 0; k < 48; ++k) {
      float f = Fs[r][kc * 48 + k];
      float4 w0 = *(float4*)&Wc[k][q * 16];
      float4 w1 = *(float4*)&Wc[k][q * 16 + 4];
      float4 w2 = *(float4*)&Wc[k][q * 16 + 8];
      float4 w3 = *(float4*)&Wc[k][q * 16 + 12];
      acc[0]  += f * w0.x; acc[1]  += f * w0.y; acc[2]  += f * w0.z; acc[3]  += f * w0.w;
      acc[4]  += f * w1.x; acc[5]  += f * w1.y; acc[6]  += f * w1.z; acc[7]  += f * w1.w;
      acc[8]  += f * w2.x; acc[9]  += f * w2.y; acc[10] += f * w2.z; acc[11] += f * w2.w;
      acc[12] += f * w3.x; acc[13] += f * w3.y; acc[14] += f * w3.z; acc[15] += f * w3.w;
    }
  }
  size_t g = (size_t)(rowbase + r);
  if (q < 4) {  // reset half -> RH = r*h
#pragma unroll
    for (int jj = 0; jj < 16; ++jj) {
      int c = q * 16 + jj;
      float rr_ = sigm(acc[jj] + bgs[c]);
      float rhv = rr_ * Fs[r][16 + c];
      RH[g * 64 + c] = rhv;
      Ts[c][r] = rhv;
    }
  } else {      // update half -> U
#pragma unroll
    for (int jj = 0; jj < 16; ++jj) {
      int c = (q - 4) * 16 + jj;
      U[g * 64 + c] = sigm(acc[jj] + bgs[64 + c]);
    }
  }
  __syncthreads();
  {
    const int c = threadIdx.x >> 2, p = threadIdx.x & 3;
    const int n0 = rowbase & 1023;
    uint4 o;
    o.x = pk2(Ts[c][p * 8 + 0], Ts[c][p * 8 + 1]);
    o.y = pk2(Ts[c][p * 8 + 2], Ts[c][p * 8 + 3]);
    o.z = pk2(Ts[c][p * 8 + 4], Ts[c][p * 8 + 5]);
    o.w = pk2(Ts[c][p * 8 + 6], Ts[c][p * 8 + 7]);
    *(uint4*)(RHB + ((size_t)i * 64 + c) * 1024 + n0 + p * 8) = o;
  }
}

// ---------------------------------------------------------------- candidate tail + state update (+ SB mirror)
__global__ __launch_bounds__(256) void k_cand_tail(const float* __restrict__ values,
    const float* __restrict__ masks, float* __restrict__ S, unsigned short* __restrict__ SB,
    const float* __restrict__ HHS, const float* __restrict__ HHX,
    const float* __restrict__ RH, const float* __restrict__ U,
    const float* __restrict__ vWc, const float* __restrict__ vbc,
    const float* __restrict__ gWc, const float* __restrict__ gbc, int t) {
  __shared__ float Fs[32][248];
  __shared__ float Wc[48][64];
  __shared__ float bcs[64];
  __shared__ float Ms[32];
  __shared__ float Ts[64][33];
  const int rowbase = blockIdx.x * 32;
  const int i = rowbase >> 10, st = i >> 3, b = i & 7;
  const float* Wcc = st ? gWc : vWc;
  const float* bc = st ? gbc : vbc;
  const int r = threadIdx.x >> 3, q = threadIdx.x & 7;

  for (int idx = threadIdx.x; idx < 32 * 80; idx += 256) {
    int rr = idx / 80, c = idx - rr * 80;
    size_t g = (size_t)(rowbase + rr);
    int n = (int)(g & 1023);
    float xh, v1, v2;
    if (c < 16) {
      size_t xo = ((((size_t)b * T_ + t) << 10) + n) * 16 + c;
      xh = values[xo] * masks[xo];
      v1 = HHX[((size_t)b * 2048 + n) * 16 + c];
      v2 = HHX[((size_t)b * 2048 + 1024 + n) * 16 + c];
    } else {
      xh = RH[g * 64 + (c - 16)];
      v1 = HHS[((size_t)i * 2048 + n) * 64 + (c - 16)];
      v2 = HHS[((size_t)i * 2048 + 1024 + n) * 64 + (c - 16)];
    }
    Fs[rr][c] = xh;
    Fs[rr][80 + c]  = v1;
    Fs[rr][160 + c] = v2;
  }
  if (threadIdx.x < 64) bcs[threadIdx.x] = bc[threadIdx.x];
  if (threadIdx.x < 32) {
    int n = (rowbase + threadIdx.x) & 1023;
    size_t xo = ((((size_t)b * T_ + t) << 10) + n) * 16;
    float s = 0.0f;
    for (int d = 0; d < 16; ++d) s += fabsf(masks[xo + d]);
    Ms[threadIdx.x] = (s > 1e-4f) ? 1.0f : 0.0f;
  }

  float acc[8];
#pragma unroll
  for (int j = 0; j < 8; ++j) acc[j] = 0.0f;
  for (int kc = 0; kc < 5; ++kc) {
    __syncthreads();
    for (int idx = threadIdx.x; idx < 768; idx += 256)
      ((float4*)Wc)[idx] = ((const float4*)Wcc)[kc * 768 + idx];
    __syncthreads();
#pragma unroll 8
    for (int k = 0; k < 48; ++k) {
      float f = Fs[r][kc * 48 + k];
      float4 w0 = *(float4*)&Wc[k][q * 8];
      float4 w1 = *(float4*)&Wc[k][q * 8 + 4];
      acc[0] += f * w0.x; acc[1] += f * w0.y; acc[2] += f * w0.z; acc[3] += f * w0.w;
      acc[4] += f * w1.x; acc[5] += f * w1.y; acc[6] += f * w1.z; acc[7] += f * w1.w;
    }
  }
  size_t g = (size_t)(rowbase + r);
  float m = Ms[r];
#pragma unroll
  for (int jj = 0; jj < 8; ++jj) {
    int c = q * 8 + jj;
    float cc = tanhf(acc[jj] + bcs[c]);
    float h1 = S[g * 64 + c];
    float u  = U[g * 64 + c];
    float h2 = u * h1 + (1.0f - u) * cc;
    float ns = h1 * (1.0f - m) + h2 * m;
    S[g * 64 + c] = ns;
    Ts[c][r] = ns;
  }
  __syncthreads();
  {
    const int c = threadIdx.x >> 2, p = threadIdx.x & 3;
    const int n0 = rowbase & 1023;
    uint4 o;
    o.x = pk2(Ts[c][p * 8 + 0], Ts[c][p * 8 + 1]);
    o.y = pk2(Ts[c][p * 8 + 2], Ts[c][p * 8 + 3]);
    o.z = pk2(Ts[c][p * 8 + 4], Ts[c][p * 8 + 5]);
    o.w = pk2(Ts[c][p * 8 + 6], Ts[c][p * 8 + 7]);
    *(uint4*)(SB + ((size_t)i * 64 + c) * 1024 + n0 + p * 8) = o;
  }
}

// ---------------------------------------------------------------- output tail
__global__ __launch_bounds__(256) void k_out(const float* __restrict__ S,
    const float* __restrict__ Wz1, const float* __restrict__ bz1,
    const float* __restrict__ Wz2, const float* __restrict__ bz2,
    const float* __restrict__ Wz3, const float* __restrict__ bz3,
    const float* __restrict__ Wo, const float* __restrict__ bo,
    float* __restrict__ out, int t) {
  __shared__ float Zs[32][68];
  __shared__ float T1s[32][68];
  __shared__ float Hs[32][68];
  __shared__ float Wc[64][64];
  __shared__ float bias[64];
  const int rowbase = blockIdx.x * 32;
  const int r = threadIdx.x >> 3, q = threadIdx.x & 7;

  for (int idx = threadIdx.x; idx < 2048; idx += 256) {
    int rr = idx >> 6, c = idx & 63;
    size_t g = (size_t)(rowbase + rr);
    Zs[rr][c] = S[(size_t)524288 + g * 64 + c];
    Hs[rr][c] = S[g * 64 + c];
  }

#define LAYER(SRC, DST, WPTR, BPTR, ACT)                                            \
  __syncthreads();                                                                  \
  for (int idx = threadIdx.x; idx < 1024; idx += 256)                               \
    ((float4*)Wc)[idx] = ((const float4*)(WPTR))[idx];                              \
  if (threadIdx.x < 64) bias[threadIdx.x] = (BPTR)[threadIdx.x];                    \
  __syncthreads();                                                                  \
  {                                                                                 \
    float ac[8] = {0, 0, 0, 0, 0, 0, 0, 0};                                         \
    _Pragma("unroll 8") for (int k = 0; k < 64; ++k) {                              \
      float f = SRC[r][k];                                                          \
      float4 w0 = *(float4*)&Wc[k][q * 8];                                          \
      float4 w1 = *(float4*)&Wc[k][q * 8 + 4];                                      \
      ac[0] += f * w0.x; ac[1] += f * w0.y; ac[2] += f * w0.z; ac[3] += f * w0.w;   \
      ac[4] += f * w1.x; ac[5] += f * w1.y; ac[6] += f * w1.z; ac[7] += f * w1.w;   \
    }                                                                               \
    _Pragma("unroll") for (int j = 0; j < 8; ++j)                                   \
        DST[r][q * 8 + j] = ACT(ac[j] + bias[q * 8 + j]);                           \
  }

  LAYER(Zs, T1s, Wz1, bz1, tanhf)
  LAYER(T1s, Zs, Wz2, bz2, tanhf)
  LAYER(Zs, T1s, Wz3, bz3, sigm)
#undef LAYER

  __syncthreads();
  for (int idx = threadIdx.x; idx < 256; idx += 256)
    ((float4*)Wc)[idx] = ((const float4*)Wo)[idx];
  if (threadIdx.x < 16) bias[threadIdx.x] = bo[threadIdx.x];
  __syncthreads();

  const float* WcF = &Wc[0][0];
  float a0 = 0.0f, a1 = 0.0f;
#pragma unroll 8
  for (int k = 0; k < 64; ++k) {
    float f = Hs[r][k] * T1s[r][k];
    a0 += f * WcF[k * 16 + q * 2];
    a1 += f * WcF[k * 16 + q * 2 + 1];
  }
  size_t g = (size_t)(rowbase + r);
  int b = (int)(g >> 10), n = (int)(g & 1023);
  size_t o = (((size_t)b * 39 + (t - 1)) * 1024 + n) * 16 + q * 2;
  out[o]     = a0 + bias[q * 2];
  out[o + 1] = a1 + bias[q * 2 + 1];
}

// ---------------------------------------------------------------- launch
extern "C" void kernel_launch(void* const* d_in, const int* in_sizes, int n_in,
                              void* d_out, int out_size, void* d_ws, size_t ws_size,
                              hipStream_t stream) {
  const float* values = (const float*)d_in[0];
  const float* masks  = (const float*)d_in[1];
  const float* A      = (const float*)d_in[2];
  const float* h0     = (const float*)d_in[3];
  const float* z0     = (const float*)d_in[4];
  const float* gV_Wg  = (const float*)d_in[5];
  const float* gV_bg  = (const float*)d_in[6];
  const float* gV_Wc  = (const float*)d_in[7];
  const float* gV_bc  = (const float*)d_in[8];
  const float* gG_Wg  = (const float*)d_in[9];
  const float* gG_bg  = (const float*)d_in[10];
  const float* gG_Wc  = (const float*)d_in[11];
  const float* gG_bc  = (const float*)d_in[12];
  const float* oV_W0  = (const float*)d_in[13];
  const float* oV_b0  = (const float*)d_in[14];
  const float* oV_Wout = (const float*)d_in[15];
  const float* oV_bout = (const float*)d_in[16];
  const float* oG_W0  = (const float*)d_in[17];
  const float* oG_b0  = (const float*)d_in[18];
  const float* oG_Wout = (const float*)d_in[19];
  const float* oG_bout = (const float*)d_in[20];
  const float* Wz1 = (const float*)d_in[21];
  const float* bz1 = (const float*)d_in[22];
  const float* Wz2 = (const float*)d_in[23];
  const float* bz2 = (const float*)d_in[24];
  const float* Wz3 = (const float*)d_in[25];
  const float* bz3 = (const float*)d_in[26];
  const float* Wo  = (const float*)d_in[27];
  const float* bo  = (const float*)d_in[28];
  float* out = (float*)d_out;

  if (ws_size < (size_t)70254592) return;
  char* ws = (char*)d_ws;
  float* S            = (float*)(ws + 0);
  float* RH           = (float*)(ws + 4194304);
  float* U            = (float*)(ws + 8388608);
  float* HHS          = (float*)(ws + 12582912);
  float* HHX          = (float*)(ws + 20971520);
  unsigned short* SB  = (unsigned short*)(ws + 22020096);
  unsigned short* RHB = (unsigned short*)(ws + 24117248);
  unsigned short* XB  = (unsigned short*)(ws + 26214400);
  unsigned short* AS  = (unsigned short*)(ws + 36700160);

  k_asA<<<4096, 256, 0, stream>>>(A, AS);
  k_a2<<<dim3(8, 8, 8), 256, 0, stream>>>(A, AS);
  k_init<<<4096, 256, 0, stream>>>(S, SB, h0, z0);
  k_xb<<<dim3(320, 4), 256, 0, stream>>>(values, masks, XB);

  for (int t = 0; t < T_; ++t) {
    for (int e = 0; e < 2; ++e) {
      k_hop_mfma<8, 0><<<dim3(32, 8), 256, 0, stream>>>(AS, XB, SB, RHB, HHS, HHX, t);
      k_ode_tail<<<512, 256, 0, stream>>>(S, SB, HHS, oV_W0, oV_b0, oV_Wout, oV_bout,
                                          oG_W0, oG_b0, oG_Wout, oG_bout);
    }
    if (t >= 1)
      k_out<<<256, 256, 0, stream>>>(S, Wz1, bz1, Wz2, bz2, Wz3, bz3, Wo, bo, out, t);
    k_hop_mfma<9, 1><<<dim3(32, 8), 256, 0, stream>>>(AS, XB, SB, RHB, HHS, HHX, t);
    k_gate_tail<<<512, 256, 0, stream>>>(values, masks, S, HHS, HHX, RH, RHB, U,
                                         gV_Wg, gV_bg, gG_Wg, gG_bg, t);
    k_hop_mfma<8, 2><<<dim3(32, 8), 256, 0, stream>>>(AS, XB, SB, RHB, HHS, HHX, t);
    k_cand_tail<<<512, 256, 0, stream>>>(values, masks, S, SB, HHS, HHX, RH, U,
                                         gV_Wc, gV_bc, gG_Wc, gG_bc, t);
  }
}

// Round 7
// 8997.449 us; speedup vs baseline: 3.7786x; 1.0525x over previous
//
#include <hip/hip_runtime.h>
#include <math.h>

// GRU-ODE / DCGRU on dense graph. B=8, T=40, N=1024, DIN=16, DR=64, DH=64, K=3.
// Round 5 (resubmit x2): round-4 fused structure + fix: B-tile staging was missing the
// per-lane k-offset (+lk*8) -> each lane-group loaded the same 8 k-values 4x. Now
// identical fragment layout to the round-3 validated hop.
//
// ws layout (bytes):
//   S    f32 [16][1024][64]    @ 0
//   RH   f32 [16][1024][64]    @ 4194304
//   U    f32 [16][1024][64]    @ 8388608
//   SBa  bf16 [16][64][1024]   @ 12582912
//   SBb  bf16 [16][64][1024]   @ 14680064
//   RHB  bf16 [16][64][1024]   @ 16777216
//   XB   bf16 [320][16][1024]  @ 18874368
//   AS   bf16 [8][2048][1024]  @ 29360128   (rows 0..1023 = A, 1024.. = A2)
//   total 62914560 B

#define T_ 40

typedef __attribute__((ext_vector_type(8))) short short8;
typedef __attribute__((ext_vector_type(4))) float f32x4;

__device__ __forceinline__ float sigm(float x) { return 1.0f / (1.0f + expf(-x)); }

__device__ __forceinline__ unsigned short bfrnd(float x) {
  union { float f; unsigned int u; } v; v.f = x;
  unsigned int u = v.u + 0x7fffu + ((v.u >> 16) & 1u);
  return (unsigned short)(u >> 16);
}
__device__ __forceinline__ unsigned int pk2(float a, float b) {
  return (unsigned int)bfrnd(a) | ((unsigned int)bfrnd(b) << 16);
}

// ---------------------------------------------------------------- init S + SBa mirror
__global__ __launch_bounds__(256) void k_init(float* __restrict__ S, unsigned short* __restrict__ SB,
                                              const float* __restrict__ h0,
                                              const float* __restrict__ z0) {
  int idx = blockIdx.x * 256 + threadIdx.x;
  int c = idx & 63;
  S[idx] = (idx < (8192 * 64)) ? h0[c] : z0[c];
  int cc = (idx >> 10) & 63;
  float v2 = ((idx >> 16) < 8) ? h0[cc] : z0[cc];
  SB[idx] = bfrnd(v2);
}

// ---------------------------------------------------------------- A rows -> bf16 AS
__global__ __launch_bounds__(256) void k_asA(const float* __restrict__ A, unsigned short* __restrict__ AS) {
  size_t j = ((size_t)blockIdx.x * 256 + threadIdx.x) * 8;
  if (j >= (size_t)8 * 1024 * 1024) return;
  int b = (int)(j >> 20);
  size_t rem = j & 1048575;
  int r = (int)(rem >> 10), k = (int)(rem & 1023);
  const float* src = A + ((size_t)b << 20) + (size_t)r * 1024 + k;
  float4 v0 = *(const float4*)src;
  float4 v1 = *(const float4*)(src + 4);
  uint4 o;
  o.x = pk2(v0.x, v0.y); o.y = pk2(v0.z, v0.w);
  o.z = pk2(v1.x, v1.y); o.w = pk2(v1.z, v1.w);
  *(uint4*)(AS + ((size_t)b * 2048 + r) * 1024 + k) = o;
}

// ---------------------------------------------------------------- XB: col-major bf16 x
__global__ __launch_bounds__(256) void k_xb(const float* __restrict__ values,
                                            const float* __restrict__ masks,
                                            unsigned short* __restrict__ XB) {
  const int bt = blockIdx.x;
  const int n0 = blockIdx.y * 256;
  __shared__ float Ls[256][17];
  const int tid = threadIdx.x;
  size_t base = ((size_t)bt * 1024 + n0 + tid) * 16;
#pragma unroll
  for (int c4 = 0; c4 < 4; ++c4) {
    float4 v = *(const float4*)&values[base + c4 * 4];
    float4 m = *(const float4*)&masks[base + c4 * 4];
    Ls[tid][c4 * 4 + 0] = v.x * m.x; Ls[tid][c4 * 4 + 1] = v.y * m.y;
    Ls[tid][c4 * 4 + 2] = v.z * m.z; Ls[tid][c4 * 4 + 3] = v.w * m.w;
  }
  __syncthreads();
  const int c = tid >> 4, seg = tid & 15;
  uint4 o1, o2;
  o1.x = pk2(Ls[seg * 16 + 0][c], Ls[seg * 16 + 1][c]);
  o1.y = pk2(Ls[seg * 16 + 2][c], Ls[seg * 16 + 3][c]);
  o1.z = pk2(Ls[seg * 16 + 4][c], Ls[seg * 16 + 5][c]);
  o1.w = pk2(Ls[seg * 16 + 6][c], Ls[seg * 16 + 7][c]);
  o2.x = pk2(Ls[seg * 16 + 8][c], Ls[seg * 16 + 9][c]);
  o2.y = pk2(Ls[seg * 16 + 10][c], Ls[seg * 16 + 11][c]);
  o2.z = pk2(Ls[seg * 16 + 12][c], Ls[seg * 16 + 13][c]);
  o2.w = pk2(Ls[seg * 16 + 14][c], Ls[seg * 16 + 15][c]);
  unsigned short* dst = XB + ((size_t)bt * 16 + c) * 1024 + n0 + seg * 16;
  *(uint4*)dst = o1;
  *(uint4*)(dst + 8) = o2;
}

// ---------------------------------------------------------------- A2 = A @ A (fp32, bf16 store)
__global__ __launch_bounds__(256) void k_a2(const float* __restrict__ A, unsigned short* __restrict__ AS) {
  const int b = blockIdx.z;
  const int m0 = blockIdx.y * 128, n0 = blockIdx.x * 128;
  const float* Ab = A + ((size_t)b << 20);
  __shared__ float As[8][136];
  __shared__ float Bs[8][136];
  const int tx = threadIdx.x & 15, ty = threadIdx.x >> 4;
  float acc[8][8];
#pragma unroll
  for (int m = 0; m < 8; ++m)
#pragma unroll
    for (int n = 0; n < 8; ++n) acc[m][n] = 0.0f;

  for (int k0 = 0; k0 < 1024; k0 += 8) {
    int mm = threadIdx.x >> 1, k4 = (threadIdx.x & 1) * 4;
    float4 va = *(const float4*)&Ab[(size_t)(m0 + mm) * 1024 + k0 + k4];
    As[k4 + 0][mm] = va.x; As[k4 + 1][mm] = va.y; As[k4 + 2][mm] = va.z; As[k4 + 3][mm] = va.w;
    int kk = threadIdx.x >> 5, nn = (threadIdx.x & 31) * 4;
    float4 vb = *(const float4*)&Ab[(size_t)(k0 + kk) * 1024 + n0 + nn];
    *(float4*)&Bs[kk][nn] = vb;
    __syncthreads();
#pragma unroll
    for (int k = 0; k < 8; ++k) {
      float a[8], bb[8];
      *(float4*)&a[0] = *(float4*)&As[k][ty * 8];
      *(float4*)&a[4] = *(float4*)&As[k][ty * 8 + 4];
      *(float4*)&bb[0] = *(float4*)&Bs[k][tx * 8];
      *(float4*)&bb[4] = *(float4*)&Bs[k][tx * 8 + 4];
#pragma unroll
      for (int m = 0; m < 8; ++m)
#pragma unroll
        for (int n = 0; n < 8; ++n) acc[m][n] += a[m] * bb[n];
    }
    __syncthreads();
  }
#pragma unroll
  for (int m = 0; m < 8; ++m) {
    unsigned short* C = AS + ((size_t)b * 2048 + 1024 + m0 + ty * 8 + m) * 1024 + n0 + tx * 8;
    uint4 o;
    o.x = pk2(acc[m][0], acc[m][1]); o.y = pk2(acc[m][2], acc[m][3]);
    o.z = pk2(acc[m][4], acc[m][5]); o.w = pk2(acc[m][6], acc[m][7]);
    *(uint4*)C = o;
  }
}

// ---------------------------------------------------------------- fused hop + tail
// MODE 0: Euler+ODE (NT=8, K=192 tail); MODE 1: gate (NT=9, K=240); MODE 2: cand (NT=9, K=240)
template <int MODE>
__global__ __launch_bounds__(256) void k_fused(
    const unsigned short* __restrict__ AS,
    const unsigned short* __restrict__ XB,
    const unsigned short* __restrict__ SBr,
    unsigned short* __restrict__ SBw,
    const unsigned short* __restrict__ RHBin,
    unsigned short* __restrict__ RHBout,
    float* __restrict__ S, float* __restrict__ RH, float* __restrict__ U,
    const float* __restrict__ values, const float* __restrict__ masks,
    const float* __restrict__ W1h, const float* __restrict__ b1h,
    const float* __restrict__ W2h, const float* __restrict__ b2h,
    const float* __restrict__ W1z, const float* __restrict__ b1z,
    const float* __restrict__ W2z, const float* __restrict__ b2z,
    int t) {
  constexpr int NT = (MODE == 0) ? 8 : 9;
  constexpr int KF = (MODE == 0) ? 192 : 240;
  constexpr int FW = KF + 1;
  constexpr int NTILE = 2 + NT;
  constexpr int CHK = (MODE == 0) ? 64 : 48;       // W chunk k-rows
  constexpr int CW = (MODE == 1) ? 128 : 64;       // W cols
  constexpr int CWP = CW + 4;
  constexpr int NCHK = KF / CHK;
  constexpr int R0_STAGE = 2 * NTILE * 1024;
  constexpr int R0_W = CHK * CWP * 4 + ((MODE == 0) ? 16 * 68 * 4 : 0);
  constexpr int R0 = (R0_STAGE > R0_W) ? R0_STAGE : R0_W;

  __shared__ __align__(16) char r0[R0];
  __shared__ float feats[2][16][FW];
  __shared__ float Ts[2][64][17];
  __shared__ float Ms[16];

  unsigned short* stg = (unsigned short*)r0;
  float* Wcs = (float*)r0;
  float* T1 = (float*)(r0 + 64 * 68 * 4);   // mode0 only: [16][68] after Wcs

  const int tid = threadIdx.x;
  const int w = tid >> 6, l = tid & 63;
  const int lr = l & 15, lk = l >> 4;
  const int b = blockIdx.y;
  const int n0 = blockIdx.x * 16;

  // --- A-tile per-lane global srcs (frag-linear) ---
  const unsigned short* ag =
      AS + ((size_t)b * 2048 + (w == 1 ? 1024 : 0) + n0 + lr) * 1024 + lk * 8;

  // --- B-tile srcs (col-major [c][n]); per-lane: col=lr, k-offset lk*8 (FIX vs r4) ---
  auto tsrc = [&](int ct) -> const unsigned short* {
    if (MODE == 0) {
      int st = ct >> 2, cl = ct & 3;
      return SBr + ((size_t)(st * 8 + b) * 64 + cl * 16 + lr) * 1024 + lk * 8;
    } else {
      if (ct == 0) return XB + ((size_t)(b * T_ + t) * 16 + lr) * 1024 + lk * 8;
      const unsigned short* base = (MODE == 1) ? SBr : RHBin;
      int st = (ct <= 4) ? 0 : 1;
      int cl = (ct <= 4) ? (ct - 1) : (ct - 5);
      return base + ((size_t)(st * 8 + b) * 64 + cl * 16 + lr) * 1024 + lk * 8;
    }
  };
  const unsigned short* bs0 = tsrc(w);
  const unsigned short* bs1 = tsrc(w + 4);
  const unsigned short* bs2 = (NT == 9 && w == 0) ? tsrc(8) : bs0;
  const int bcnt = (NT == 9 && w == 0) ? 3 : 2;

  // --- feats direct parts (global loads, before staging barrier) ---
  if (MODE == 0) {
    for (int idx = tid; idx < 512; idx += 256) {
      int st = idx >> 8, rr = (idx >> 4) & 15, c4 = idx & 15;
      float4 v = *(const float4*)&S[((size_t)(st * 8 + b) * 1024 + n0 + rr) * 64 + c4 * 4];
      feats[st][rr][c4 * 4 + 0] = v.x; feats[st][rr][c4 * 4 + 1] = v.y;
      feats[st][rr][c4 * 4 + 2] = v.z; feats[st][rr][c4 * 4 + 3] = v.w;
    }
  } else {
    for (int idx = tid; idx < 64; idx += 256) {
      int rr = idx >> 2, c4 = idx & 3;
      size_t xo = ((size_t)(b * T_ + t) * 1024 + n0 + rr) * 16 + c4 * 4;
      float4 v = *(const float4*)&values[xo];
      float4 m = *(const float4*)&masks[xo];
      float xv[4] = {v.x * m.x, v.y * m.y, v.z * m.z, v.w * m.w};
#pragma unroll
      for (int j = 0; j < 4; ++j) {
        feats[0][rr][c4 * 4 + j] = xv[j];
        feats[1][rr][c4 * 4 + j] = xv[j];
      }
    }
    const float* bp = (MODE == 1) ? S : RH;
    for (int idx = tid; idx < 512; idx += 256) {
      int st = idx >> 8, rr = (idx >> 4) & 15, c4 = idx & 15;
      float4 v = *(const float4*)&bp[((size_t)(st * 8 + b) * 1024 + n0 + rr) * 64 + c4 * 4];
      feats[st][rr][16 + c4 * 4 + 0] = v.x; feats[st][rr][16 + c4 * 4 + 1] = v.y;
      feats[st][rr][16 + c4 * 4 + 2] = v.z; feats[st][rr][16 + c4 * 4 + 3] = v.w;
    }
  }
  if (MODE == 2 && tid < 16) {
    int n = n0 + tid;
    size_t xo = ((size_t)(b * T_ + t) * 1024 + n) * 16;
    float s = 0.0f;
    for (int d = 0; d < 16; ++d) s += fabsf(masks[xo + d]);
    Ms[tid] = (s > 1e-4f) ? 1.0f : 0.0f;
  }

  // --- MFMA K-loop ---
  f32x4 acc[2][3];
#pragma unroll
  for (int rt = 0; rt < 2; ++rt)
#pragma unroll
    for (int ci = 0; ci < 3; ++ci) acc[rt][ci] = (f32x4){0.f, 0.f, 0.f, 0.f};

#define GLD(SRC, SLOT, BUF)                                                                   \
  __builtin_amdgcn_global_load_lds(                                                           \
      (const __attribute__((address_space(1))) void*)(SRC),                                   \
      (__attribute__((address_space(3))) void*)(stg + ((BUF)*NTILE + (SLOT)) * 512), 16, 0, 0)

#define STAGE(BUF, K0)                                                                        \
  {                                                                                           \
    if (w < 2) GLD(ag + (K0), w, BUF);                                                        \
    GLD(bs0 + (K0), 2 + w, BUF);                                                              \
    GLD(bs1 + (K0), 2 + w + 4, BUF);                                                          \
    if (NT == 9 && w == 0) GLD(bs2 + (K0), 2 + 8, BUF);                                       \
  }

  int cur = 0;
  STAGE(0, 0)
  __syncthreads();
  for (int step = 0; step < 32; ++step) {
    const int nxt = cur ^ 1;
    if (step < 31) STAGE(nxt, (step + 1) * 32)
    short8 a0f = *(const short8*)&stg[(cur * NTILE + 0) * 512 + l * 8];
    short8 a1f = *(const short8*)&stg[(cur * NTILE + 1) * 512 + l * 8];
    short8 b0f = *(const short8*)&stg[(cur * NTILE + 2 + w) * 512 + l * 8];
    short8 b1f = *(const short8*)&stg[(cur * NTILE + 2 + w + 4) * 512 + l * 8];
    acc[0][0] = __builtin_amdgcn_mfma_f32_16x16x32_bf16(a0f, b0f, acc[0][0], 0, 0, 0);
    acc[1][0] = __builtin_amdgcn_mfma_f32_16x16x32_bf16(a1f, b0f, acc[1][0], 0, 0, 0);
    acc[0][1] = __builtin_amdgcn_mfma_f32_16x16x32_bf16(a0f, b1f, acc[0][1], 0, 0, 0);
    acc[1][1] = __builtin_amdgcn_mfma_f32_16x16x32_bf16(a1f, b1f, acc[1][1], 0, 0, 0);
    if (NT == 9 && w == 0) {
      short8 b2f = *(const short8*)&stg[(cur * NTILE + 2 + 8) * 512 + l * 8];
      acc[0][2] = __builtin_amdgcn_mfma_f32_16x16x32_bf16(a0f, b2f, acc[0][2], 0, 0, 0);
      acc[1][2] = __builtin_amdgcn_mfma_f32_16x16x32_bf16(a1f, b2f, acc[1][2], 0, 0, 0);
    }
    __syncthreads();
    cur = nxt;
  }
#undef STAGE
#undef GLD

  // --- fragments -> feats ---
#pragma unroll
  for (int ci = 0; ci < 3; ++ci) {
    if (ci < bcnt) {
      const int ct = w + ci * 4;
#pragma unroll
      for (int rt = 0; rt < 2; ++rt) {
#pragma unroll
        for (int j = 0; j < 4; ++j) {
          float v = acc[rt][ci][j];
          int row = lk * 4 + j;
          if (MODE == 0) {
            int st = ct >> 2;
            feats[st][row][64 + rt * 64 + (ct & 3) * 16 + lr] = v;
          } else {
            if (ct == 0) {
              int col = 80 + rt * 80 + lr;
              feats[0][row][col] = v;
              feats[1][row][col] = v;
            } else {
              int st = (ct <= 4) ? 0 : 1;
              int cl = (ct <= 4) ? (ct - 1) : (ct - 5);
              feats[st][row][80 + rt * 80 + 16 + cl * 16 + lr] = v;
            }
          }
        }
      }
    }
  }
  __syncthreads();

  // ================= tails (fp32) =================
  const int r_ = tid >> 4, cq = tid & 15;

  if (MODE == 0) {
    for (int st = 0; st < 2; ++st) {
      const float* W1 = st ? W1z : W1h;
      const float* B1 = st ? b1z : b1h;
      const float* W2 = st ? W2z : W2h;
      const float* B2 = st ? b2z : b2h;
      float a4[4] = {0, 0, 0, 0};
      for (int kc = 0; kc < NCHK; ++kc) {
        __syncthreads();
        for (int idx = tid; idx < 1024; idx += 256) {
          int k = idx >> 4, c4 = idx & 15;
          *(float4*)&Wcs[k * 68 + c4 * 4] = *(const float4*)&W1[(size_t)(kc * 64 + k) * 64 + c4 * 4];
        }
        __syncthreads();
#pragma unroll 8
        for (int k = 0; k < 64; ++k) {
          float f = feats[st][r_][kc * 64 + k];
          float4 w4 = *(float4*)&Wcs[k * 68 + cq * 4];
          a4[0] += f * w4.x; a4[1] += f * w4.y; a4[2] += f * w4.z; a4[3] += f * w4.w;
        }
      }
#pragma unroll
      for (int j = 0; j < 4; ++j) T1[r_ * 68 + cq * 4 + j] = tanhf(a4[j] + B1[cq * 4 + j]);
      __syncthreads();
      for (int idx = tid; idx < 1024; idx += 256) {
        int k = idx >> 4, c4 = idx & 15;
        *(float4*)&Wcs[k * 68 + c4 * 4] = *(const float4*)&W2[(size_t)k * 64 + c4 * 4];
      }
      __syncthreads();
      float o4[4] = {0, 0, 0, 0};
#pragma unroll 8
      for (int k = 0; k < 64; ++k) {
        float f = T1[r_ * 68 + k];
        float4 w4 = *(float4*)&Wcs[k * 68 + cq * 4];
        o4[0] += f * w4.x; o4[1] += f * w4.y; o4[2] += f * w4.z; o4[3] += f * w4.w;
      }
      size_t g = ((size_t)(st * 8 + b) * 1024 + n0 + r_) * 64 + cq * 4;
#pragma unroll
      for (int j = 0; j < 4; ++j) {
        float ns = S[g + j] + 0.025f * tanhf(o4[j] + B2[cq * 4 + j]);
        S[g + j] = ns;
        Ts[st][cq * 4 + j][r_] = ns;
      }
      __syncthreads();
    }
  } else if (MODE == 1) {
    for (int st = 0; st < 2; ++st) {
      const float* W1 = st ? W1z : W1h;
      const float* B1 = st ? b1z : b1h;
      float a8[8] = {0, 0, 0, 0, 0, 0, 0, 0};
      for (int kc = 0; kc < NCHK; ++kc) {
        __syncthreads();
        for (int idx = tid; idx < 1536; idx += 256) {
          int k = idx >> 5, c4 = idx & 31;
          *(float4*)&Wcs[k * 132 + c4 * 4] = *(const float4*)&W1[(size_t)(kc * 48 + k) * 128 + c4 * 4];
        }
        __syncthreads();
#pragma unroll 8
        for (int k = 0; k < 48; ++k) {
          float f = feats[st][r_][kc * 48 + k];
          float4 wA = *(float4*)&Wcs[k * 132 + cq * 8];
          float4 wB = *(float4*)&Wcs[k * 132 + cq * 8 + 4];
          a8[0] += f * wA.x; a8[1] += f * wA.y; a8[2] += f * wA.z; a8[3] += f * wA.w;
          a8[4] += f * wB.x; a8[5] += f * wB.y; a8[6] += f * wB.z; a8[7] += f * wB.w;
        }
      }
      size_t g = ((size_t)(st * 8 + b) * 1024 + n0 + r_) * 64;
      if (cq < 8) {
#pragma unroll
        for (int j = 0; j < 8; ++j) {
          int c = cq * 8 + j;
          float rr = sigm(a8[j] + B1[c]);
          float rhv = rr * feats[st][r_][16 + c];
          RH[g + c] = rhv;
          Ts[st][c][r_] = rhv;
        }
      } else {
#pragma unroll
        for (int j = 0; j < 8; ++j) {
          int c = (cq - 8) * 8 + j;
          U[g + c] = sigm(a8[j] + B1[64 + c]);
        }
      }
      __syncthreads();
    }
  } else {
    for (int st = 0; st < 2; ++st) {
      const float* W1 = st ? W1z : W1h;
      const float* B1 = st ? b1z : b1h;
      float a4[4] = {0, 0, 0, 0};
      for (int kc = 0; kc < NCHK; ++kc) {
        __syncthreads();
        for (int idx = tid; idx < 768; idx += 256) {
          int k = idx >> 4, c4 = idx & 15;
          *(float4*)&Wcs[k * 68 + c4 * 4] = *(const float4*)&W1[(size_t)(kc * 48 + k) * 64 + c4 * 4];
        }
        __syncthreads();
#pragma unroll 8
        for (int k = 0; k < 48; ++k) {
          float f = feats[st][r_][kc * 48 + k];
          float4 w4 = *(float4*)&Wcs[k * 68 + cq * 4];
          a4[0] += f * w4.x; a4[1] += f * w4.y; a4[2] += f * w4.z; a4[3] += f * w4.w;
        }
      }
      size_t g = ((size_t)(st * 8 + b) * 1024 + n0 + r_) * 64;
      float m = Ms[r_];
#pragma unroll
      for (int j = 0; j < 4; ++j) {
        int c = cq * 4 + j;
        float cc = tanhf(a4[j] + B1[c]);
        float h1 = S[g + c];
        float u = U[g + c];
        float h2 = u * h1 + (1.0f - u) * cc;
        float ns = h1 * (1.0f - m) + h2 * m;
        S[g + c] = ns;
        Ts[st][c][r_] = ns;
      }
      __syncthreads();
    }
  }

  // --- bf16 col-major mirror write (SBw for modes 0/2, RHBout for mode 1) ---
  {
    unsigned short* dstbuf = (MODE == 1) ? RHBout : SBw;
    int st = tid >> 7, c = (tid >> 1) & 63, p = tid & 1;
    float* tp = &Ts[st][c][p * 8];
    uint4 o;
    o.x = pk2(tp[0], tp[1]); o.y = pk2(tp[2], tp[3]);
    o.z = pk2(tp[4], tp[5]); o.w = pk2(tp[6], tp[7]);
    *(uint4*)(dstbuf + ((size_t)(st * 8 + b) * 64 + c) * 1024 + n0 + p * 8) = o;
  }
}

// ---------------------------------------------------------------- output tail
__global__ __launch_bounds__(256) void k_out(const float* __restrict__ S,
    const float* __restrict__ Wz1, const float* __restrict__ bz1,
    const float* __restrict__ Wz2, const float* __restrict__ bz2,
    const float* __restrict__ Wz3, const float* __restrict__ bz3,
    const float* __restrict__ Wo, const float* __restrict__ bo,
    float* __restrict__ out, int t) {
  __shared__ float Zs[32][68];
  __shared__ float T1s[32][68];
  __shared__ float Hs[32][68];
  __shared__ float Wc[64][64];
  __shared__ float bias[64];
  const int rowbase = blockIdx.x * 32;
  const int r = threadIdx.x >> 3, q = threadIdx.x & 7;

  for (int idx = threadIdx.x; idx < 2048; idx += 256) {
    int rr = idx >> 6, c = idx & 63;
    size_t g = (size_t)(rowbase + rr);
    Zs[rr][c] = S[(size_t)524288 + g * 64 + c];
    Hs[rr][c] = S[g * 64 + c];
  }

#define LAYER(SRC, DST, WPTR, BPTR, ACT)                                            \
  __syncthreads();                                                                  \
  for (int idx = threadIdx.x; idx < 1024; idx += 256)                               \
    ((float4*)Wc)[idx] = ((const float4*)(WPTR))[idx];                              \
  if (threadIdx.x < 64) bias[threadIdx.x] = (BPTR)[threadIdx.x];                    \
  __syncthreads();                                                                  \
  {                                                                                 \
    float ac[8] = {0, 0, 0, 0, 0, 0, 0, 0};                                         \
    _Pragma("unroll 8") for (int k = 0; k < 64; ++k) {                              \
      float f = SRC[r][k];                                                          \
      float4 w0 = *(float4*)&Wc[k][q * 8];                                          \
      float4 w1 = *(float4*)&Wc[k][q * 8 + 4];                                      \
      ac[0] += f * w0.x; ac[1] += f * w0.y; ac[2] += f * w0.z; ac[3] += f * w0.w;   \
      ac[4] += f * w1.x; ac[5] += f * w1.y; ac[6] += f * w1.z; ac[7] += f * w1.w;   \
    }                                                                               \
    _Pragma("unroll") for (int j = 0; j < 8; ++j)                                   \
        DST[r][q * 8 + j] = ACT(ac[j] + bias[q * 8 + j]);                           \
  }

  LAYER(Zs, T1s, Wz1, bz1, tanhf)
  LAYER(T1s, Zs, Wz2, bz2, tanhf)
  LAYER(Zs, T1s, Wz3, bz3, sigm)
#undef LAYER

  __syncthreads();
  for (int idx = threadIdx.x; idx < 256; idx += 256)
    ((float4*)Wc)[idx] = ((const float4*)Wo)[idx];
  if (threadIdx.x < 16) bias[threadIdx.x] = bo[threadIdx.x];
  __syncthreads();

  const float* WcF = &Wc[0][0];
  float a0 = 0.0f, a1 = 0.0f;
#pragma unroll 8
  for (int k = 0; k < 64; ++k) {
    float f = Hs[r][k] * T1s[r][k];
    a0 += f * WcF[k * 16 + q * 2];
    a1 += f * WcF[k * 16 + q * 2 + 1];
  }
  size_t g = (size_t)(rowbase + r);
  int b = (int)(g >> 10), n = (int)(g & 1023);
  size_t o = (((size_t)b * 39 + (t - 1)) * 1024 + n) * 16 + q * 2;
  out[o]     = a0 + bias[q * 2];
  out[o + 1] = a1 + bias[q * 2 + 1];
}

// ---------------------------------------------------------------- launch
extern "C" void kernel_launch(void* const* d_in, const int* in_sizes, int n_in,
                              void* d_out, int out_size, void* d_ws, size_t ws_size,
                              hipStream_t stream) {
  const float* values = (const float*)d_in[0];
  const float* masks  = (const float*)d_in[1];
  const float* A      = (const float*)d_in[2];
  const float* h0     = (const float*)d_in[3];
  const float* z0     = (const float*)d_in[4];
  const float* gV_Wg  = (const float*)d_in[5];
  const float* gV_bg  = (const float*)d_in[6];
  const float* gV_Wc  = (const float*)d_in[7];
  const float* gV_bc  = (const float*)d_in[8];
  const float* gG_Wg  = (const float*)d_in[9];
  const float* gG_bg  = (const float*)d_in[10];
  const float* gG_Wc  = (const float*)d_in[11];
  const float* gG_bc  = (const float*)d_in[12];
  const float* oV_W0  = (const float*)d_in[13];
  const float* oV_b0  = (const float*)d_in[14];
  const float* oV_Wout = (const float*)d_in[15];
  const float* oV_bout = (const float*)d_in[16];
  const float* oG_W0  = (const float*)d_in[17];
  const float* oG_b0  = (const float*)d_in[18];
  const float* oG_Wout = (const float*)d_in[19];
  const float* oG_bout = (const float*)d_in[20];
  const float* Wz1 = (const float*)d_in[21];
  const float* bz1 = (const float*)d_in[22];
  const float* Wz2 = (const float*)d_in[23];
  const float* bz2 = (const float*)d_in[24];
  const float* Wz3 = (const float*)d_in[25];
  const float* bz3 = (const float*)d_in[26];
  const float* Wo  = (const float*)d_in[27];
  const float* bo  = (const float*)d_in[28];
  float* out = (float*)d_out;

  if (ws_size < (size_t)62914560) return;
  char* ws = (char*)d_ws;
  float* S            = (float*)(ws + 0);
  float* RH           = (float*)(ws + 4194304);
  float* U            = (float*)(ws + 8388608);
  unsigned short* SBa = (unsigned short*)(ws + 12582912);
  unsigned short* SBb = (unsigned short*)(ws + 14680064);
  unsigned short* RHB = (unsigned short*)(ws + 16777216);
  unsigned short* XB  = (unsigned short*)(ws + 18874368);
  unsigned short* AS  = (unsigned short*)(ws + 29360128);

  k_asA<<<4096, 256, 0, stream>>>(A, AS);
  k_a2<<<dim3(8, 8, 8), 256, 0, stream>>>(A, AS);
  k_init<<<4096, 256, 0, stream>>>(S, SBa, h0, z0);
  k_xb<<<dim3(320, 4), 256, 0, stream>>>(values, masks, XB);

  const dim3 fg(64, 8);
  for (int t = 0; t < T_; ++t) {
    k_fused<0><<<fg, 256, 0, stream>>>(AS, XB, SBa, SBb, RHB, RHB, S, RH, U, values, masks,
                                       oV_W0, oV_b0, oV_Wout, oV_bout,
                                       oG_W0, oG_b0, oG_Wout, oG_bout, t);
    k_fused<0><<<fg, 256, 0, stream>>>(AS, XB, SBb, SBa, RHB, RHB, S, RH, U, values, masks,
                                       oV_W0, oV_b0, oV_Wout, oV_bout,
                                       oG_W0, oG_b0, oG_Wout, oG_bout, t);
    if (t >= 1)
      k_out<<<256, 256, 0, stream>>>(S, Wz1, bz1, Wz2, bz2, Wz3, bz3, Wo, bo, out, t);
    if (t < T_ - 1) {
      k_fused<1><<<fg, 256, 0, stream>>>(AS, XB, SBa, SBb, RHB, RHB, S, RH, U, values, masks,
                                         gV_Wg, gV_bg, nullptr, nullptr,
                                         gG_Wg, gG_bg, nullptr, nullptr, t);
      k_fused<2><<<fg, 256, 0, stream>>>(AS, XB, SBa, SBa, RHB, RHB, S, RH, U, values, masks,
                                         gV_Wc, gV_bc, nullptr, nullptr,
                                         gG_Wc, gG_bc, nullptr, nullptr, t);
    }
  }
}

// Round 8
// 8564.227 us; speedup vs baseline: 3.9697x; 1.0506x over previous
//
#include <hip/hip_runtime.h>
#include <math.h>

// GRU-ODE / DCGRU on dense graph. B=8, T=40, N=1024, DIN=16, DR=64, DH=64, K=3.
// Round 8: (1) A^2 via bf16 MFMA (k_tr + k_a2m) replacing fp32 k_a2 (was 257us,
// MfmaUtil=0, 1.9e7 bank conflicts); (2) k_out folded into 2nd Euler kernel
// (template OUT) using Ts LDS state; (3) 1D grid, b-fastest block decode for
// per-XCD L2 locality of B-operands. MFMA hop loop + tails unchanged from r7 (passed).
//
// ws layout (bytes):
//   S    f32 [16][1024][64]    @ 0
//   RH   f32 [16][1024][64]    @ 4194304
//   U    f32 [16][1024][64]    @ 8388608
//   SBa  bf16 [16][64][1024]   @ 12582912
//   SBb  bf16 [16][64][1024]   @ 14680064
//   RHB  bf16 [16][64][1024]   @ 16777216
//   XB   bf16 [320][16][1024]  @ 18874368
//   AS   bf16 [8][2048][1024]  @ 29360128   (rows 0..1023 = A, 1024.. = A2)
//   ATB  bf16 [8][1024][1024]  @ 62914560   (A^T, bf16)
//   total 79691776 B

#define T_ 40

typedef __attribute__((ext_vector_type(8))) short short8;
typedef __attribute__((ext_vector_type(4))) float f32x4;

__device__ __forceinline__ float sigm(float x) { return 1.0f / (1.0f + expf(-x)); }

__device__ __forceinline__ unsigned short bfrnd(float x) {
  union { float f; unsigned int u; } v; v.f = x;
  unsigned int u = v.u + 0x7fffu + ((v.u >> 16) & 1u);
  return (unsigned short)(u >> 16);
}
__device__ __forceinline__ unsigned int pk2(float a, float b) {
  return (unsigned int)bfrnd(a) | ((unsigned int)bfrnd(b) << 16);
}

// ---------------------------------------------------------------- init S + SBa mirror
__global__ __launch_bounds__(256) void k_init(float* __restrict__ S, unsigned short* __restrict__ SB,
                                              const float* __restrict__ h0,
                                              const float* __restrict__ z0) {
  int idx = blockIdx.x * 256 + threadIdx.x;
  int c = idx & 63;
  S[idx] = (idx < (8192 * 64)) ? h0[c] : z0[c];
  int cc = (idx >> 10) & 63;
  float v2 = ((idx >> 16) < 8) ? h0[cc] : z0[cc];
  SB[idx] = bfrnd(v2);
}

// ---------------------------------------------------------------- A rows -> bf16 AS
__global__ __launch_bounds__(256) void k_asA(const float* __restrict__ A, unsigned short* __restrict__ AS) {
  size_t j = ((size_t)blockIdx.x * 256 + threadIdx.x) * 8;
  if (j >= (size_t)8 * 1024 * 1024) return;
  int b = (int)(j >> 20);
  size_t rem = j & 1048575;
  int r = (int)(rem >> 10), k = (int)(rem & 1023);
  const float* src = A + ((size_t)b << 20) + (size_t)r * 1024 + k;
  float4 v0 = *(const float4*)src;
  float4 v1 = *(const float4*)(src + 4);
  uint4 o;
  o.x = pk2(v0.x, v0.y); o.y = pk2(v0.z, v0.w);
  o.z = pk2(v1.x, v1.y); o.w = pk2(v1.z, v1.w);
  *(uint4*)(AS + ((size_t)b * 2048 + r) * 1024 + k) = o;
}

// ---------------------------------------------------------------- A^T -> bf16 ATB
__global__ __launch_bounds__(256) void k_tr(const float* __restrict__ A, unsigned short* __restrict__ ATB) {
  const int b = blockIdx.z, k0 = blockIdx.y * 64, n0 = blockIdx.x * 64;
  __shared__ float Ls[64][65];
  const float* Ab = A + ((size_t)b << 20);
  for (int idx = threadIdx.x; idx < 1024; idx += 256) {
    int kr = idx >> 4, cg = idx & 15;
    float4 v = *(const float4*)&Ab[(size_t)(k0 + kr) * 1024 + n0 + cg * 4];
    Ls[kr][cg * 4 + 0] = v.x; Ls[kr][cg * 4 + 1] = v.y;
    Ls[kr][cg * 4 + 2] = v.z; Ls[kr][cg * 4 + 3] = v.w;
  }
  __syncthreads();
  const int nr = threadIdx.x >> 2, seg = threadIdx.x & 3;
  const int ks = seg * 16;
  uint4 o1, o2;
  o1.x = pk2(Ls[ks + 0][nr], Ls[ks + 1][nr]);
  o1.y = pk2(Ls[ks + 2][nr], Ls[ks + 3][nr]);
  o1.z = pk2(Ls[ks + 4][nr], Ls[ks + 5][nr]);
  o1.w = pk2(Ls[ks + 6][nr], Ls[ks + 7][nr]);
  o2.x = pk2(Ls[ks + 8][nr], Ls[ks + 9][nr]);
  o2.y = pk2(Ls[ks + 10][nr], Ls[ks + 11][nr]);
  o2.z = pk2(Ls[ks + 12][nr], Ls[ks + 13][nr]);
  o2.w = pk2(Ls[ks + 14][nr], Ls[ks + 15][nr]);
  unsigned short* dst = ATB + ((size_t)b * 1024 + n0 + nr) * 1024 + k0 + ks;
  *(uint4*)dst = o1;
  *(uint4*)(dst + 8) = o2;
}

// ---------------------------------------------------------------- A2 = A@A via bf16 MFMA
// Reads AS rows 0..1023 (A) as A-frags and ATB as B-frags; writes AS rows 1024..2047.
__global__ __launch_bounds__(256) void k_a2m(unsigned short* __restrict__ AS,
                                             const unsigned short* __restrict__ ATB) {
  __shared__ __align__(16) unsigned short stg[2][12][512];
  const int tid = threadIdx.x;
  const int w = tid >> 6, l = tid & 63;
  const int lr = l & 15, lk = l >> 4;
  const int b = blockIdx.z, m0 = blockIdx.y * 64, n0 = blockIdx.x * 128;

  const unsigned short* ag  = AS  + ((size_t)b * 2048 + m0 + w * 16 + lr) * 1024 + lk * 8;
  const unsigned short* bg0 = ATB + ((size_t)b * 1024 + n0 + w * 16 + lr) * 1024 + lk * 8;
  const unsigned short* bg1 = ATB + ((size_t)b * 1024 + n0 + (w + 4) * 16 + lr) * 1024 + lk * 8;

  f32x4 acc[8];
#pragma unroll
  for (int ct = 0; ct < 8; ++ct) acc[ct] = (f32x4){0.f, 0.f, 0.f, 0.f};

#define GLD2(SRC, SLOT, BUF)                                                                  \
  __builtin_amdgcn_global_load_lds(                                                          \
      (const __attribute__((address_space(1))) void*)(SRC),                                   \
      (__attribute__((address_space(3))) void*)(&stg[BUF][SLOT][0]), 16, 0, 0)

  int cur = 0;
  GLD2(ag, w, 0); GLD2(bg0, 4 + w, 0); GLD2(bg1, 8 + w, 0);
  __syncthreads();
  for (int step = 0; step < 32; ++step) {
    const int nxt = cur ^ 1;
    if (step < 31) {
      const int K0 = (step + 1) * 32;
      GLD2(ag + K0, w, nxt); GLD2(bg0 + K0, 4 + w, nxt); GLD2(bg1 + K0, 8 + w, nxt);
    }
    short8 af = *(const short8*)&stg[cur][w][l * 8];
#pragma unroll
    for (int ct = 0; ct < 8; ++ct) {
      short8 bf = *(const short8*)&stg[cur][4 + ct][l * 8];
      acc[ct] = __builtin_amdgcn_mfma_f32_16x16x32_bf16(af, bf, acc[ct], 0, 0, 0);
    }
    __syncthreads();
    cur = nxt;
  }
#undef GLD2

#pragma unroll
  for (int ct = 0; ct < 8; ++ct) {
#pragma unroll
    for (int j = 0; j < 4; ++j) {
      AS[((size_t)b * 2048 + 1024 + m0 + w * 16 + lk * 4 + j) * 1024 + n0 + ct * 16 + lr] =
          bfrnd(acc[ct][j]);
    }
  }
}

// ---------------------------------------------------------------- XB: col-major bf16 x
__global__ __launch_bounds__(256) void k_xb(const float* __restrict__ values,
                                            const float* __restrict__ masks,
                                            unsigned short* __restrict__ XB) {
  const int bt = blockIdx.x;
  const int n0 = blockIdx.y * 256;
  __shared__ float Ls[256][17];
  const int tid = threadIdx.x;
  size_t base = ((size_t)bt * 1024 + n0 + tid) * 16;
#pragma unroll
  for (int c4 = 0; c4 < 4; ++c4) {
    float4 v = *(const float4*)&values[base + c4 * 4];
    float4 m = *(const float4*)&masks[base + c4 * 4];
    Ls[tid][c4 * 4 + 0] = v.x * m.x; Ls[tid][c4 * 4 + 1] = v.y * m.y;
    Ls[tid][c4 * 4 + 2] = v.z * m.z; Ls[tid][c4 * 4 + 3] = v.w * m.w;
  }
  __syncthreads();
  const int c = tid >> 4, seg = tid & 15;
  uint4 o1, o2;
  o1.x = pk2(Ls[seg * 16 + 0][c], Ls[seg * 16 + 1][c]);
  o1.y = pk2(Ls[seg * 16 + 2][c], Ls[seg * 16 + 3][c]);
  o1.z = pk2(Ls[seg * 16 + 4][c], Ls[seg * 16 + 5][c]);
  o1.w = pk2(Ls[seg * 16 + 6][c], Ls[seg * 16 + 7][c]);
  o2.x = pk2(Ls[seg * 16 + 8][c], Ls[seg * 16 + 9][c]);
  o2.y = pk2(Ls[seg * 16 + 10][c], Ls[seg * 16 + 11][c]);
  o2.z = pk2(Ls[seg * 16 + 12][c], Ls[seg * 16 + 13][c]);
  o2.w = pk2(Ls[seg * 16 + 14][c], Ls[seg * 16 + 15][c]);
  unsigned short* dst = XB + ((size_t)bt * 16 + c) * 1024 + n0 + seg * 16;
  *(uint4*)dst = o1;
  *(uint4*)(dst + 8) = o2;
}

// ---------------------------------------------------------------- fused hop + tail
// MODE 0: Euler+ODE (NT=8); MODE 1: gate (NT=9); MODE 2: cand (NT=9)
// OUT=1 (mode 0 only): append gate-chain + output projection for slice t-1.
template <int MODE, int OUT>
__global__ __launch_bounds__(256) void k_fused(
    const unsigned short* __restrict__ AS,
    const unsigned short* __restrict__ XB,
    const unsigned short* __restrict__ SBr,
    unsigned short* __restrict__ SBw,
    const unsigned short* __restrict__ RHBin,
    unsigned short* __restrict__ RHBout,
    float* __restrict__ S, float* __restrict__ RH, float* __restrict__ U,
    const float* __restrict__ values, const float* __restrict__ masks,
    const float* __restrict__ W1h, const float* __restrict__ b1h,
    const float* __restrict__ W2h, const float* __restrict__ b2h,
    const float* __restrict__ W1z, const float* __restrict__ b1z,
    const float* __restrict__ W2z, const float* __restrict__ b2z,
    const float* __restrict__ Wz1, const float* __restrict__ bz1,
    const float* __restrict__ Wz2, const float* __restrict__ bz2,
    const float* __restrict__ Wz3, const float* __restrict__ bz3,
    const float* __restrict__ Wo, const float* __restrict__ bo,
    float* __restrict__ outp, int t) {
  constexpr int NT = (MODE == 0) ? 8 : 9;
  constexpr int KF = (MODE == 0) ? 192 : 240;
  constexpr int FW = KF + 1;
  constexpr int NTILE = 2 + NT;
  constexpr int CHK = (MODE == 0) ? 64 : 48;       // W chunk k-rows
  constexpr int CW = (MODE == 1) ? 128 : 64;       // W cols
  constexpr int CWP = CW + 4;
  constexpr int NCHK = KF / CHK;
  constexpr int R0_STAGE = 2 * NTILE * 1024;
  constexpr int R0_W = CHK * CWP * 4 + ((MODE == 0) ? 16 * 68 * 4 : 0);
  constexpr int R0 = (R0_STAGE > R0_W) ? R0_STAGE : R0_W;

  __shared__ __align__(16) char r0[R0];
  __shared__ float feats[2][16][FW];
  __shared__ float Ts[2][64][17];
  __shared__ float Ms[16];
  __shared__ float gb[64];

  unsigned short* stg = (unsigned short*)r0;
  float* Wcs = (float*)r0;
  float* T1 = (float*)(r0 + 64 * 68 * 4);   // mode0 only: [16][68] after Wcs

  const int tid = threadIdx.x;
  const int w = tid >> 6, l = tid & 63;
  const int lr = l & 15, lk = l >> 4;
  const int b = blockIdx.x & 7;            // b fastest -> per-XCD L2 locality
  const int n0 = (blockIdx.x >> 3) * 16;

  // --- A-tile per-lane global srcs (frag-linear) ---
  const unsigned short* ag =
      AS + ((size_t)b * 2048 + (w == 1 ? 1024 : 0) + n0 + lr) * 1024 + lk * 8;

  // --- B-tile srcs (col-major [c][n]); per-lane: col=lr, k-offset lk*8 ---
  auto tsrc = [&](int ct) -> const unsigned short* {
    if (MODE == 0) {
      int st = ct >> 2, cl = ct & 3;
      return SBr + ((size_t)(st * 8 + b) * 64 + cl * 16 + lr) * 1024 + lk * 8;
    } else {
      if (ct == 0) return XB + ((size_t)(b * T_ + t) * 16 + lr) * 1024 + lk * 8;
      const unsigned short* base = (MODE == 1) ? SBr : RHBin;
      int st = (ct <= 4) ? 0 : 1;
      int cl = (ct <= 4) ? (ct - 1) : (ct - 5);
      return base + ((size_t)(st * 8 + b) * 64 + cl * 16 + lr) * 1024 + lk * 8;
    }
  };
  const unsigned short* bs0 = tsrc(w);
  const unsigned short* bs1 = tsrc(w + 4);
  const unsigned short* bs2 = (NT == 9 && w == 0) ? tsrc(8) : bs0;
  const int bcnt = (NT == 9 && w == 0) ? 3 : 2;

  // --- feats direct parts (global loads, before staging barrier) ---
  if (MODE == 0) {
    for (int idx = tid; idx < 512; idx += 256) {
      int st = idx >> 8, rr = (idx >> 4) & 15, c4 = idx & 15;
      float4 v = *(const float4*)&S[((size_t)(st * 8 + b) * 1024 + n0 + rr) * 64 + c4 * 4];
      feats[st][rr][c4 * 4 + 0] = v.x; feats[st][rr][c4 * 4 + 1] = v.y;
      feats[st][rr][c4 * 4 + 2] = v.z; feats[st][rr][c4 * 4 + 3] = v.w;
    }
  } else {
    for (int idx = tid; idx < 64; idx += 256) {
      int rr = idx >> 2, c4 = idx & 3;
      size_t xo = ((size_t)(b * T_ + t) * 1024 + n0 + rr) * 16 + c4 * 4;
      float4 v = *(const float4*)&values[xo];
      float4 m = *(const float4*)&masks[xo];
      float xv[4] = {v.x * m.x, v.y * m.y, v.z * m.z, v.w * m.w};
#pragma unroll
      for (int j = 0; j < 4; ++j) {
        feats[0][rr][c4 * 4 + j] = xv[j];
        feats[1][rr][c4 * 4 + j] = xv[j];
      }
    }
    const float* bp = (MODE == 1) ? S : RH;
    for (int idx = tid; idx < 512; idx += 256) {
      int st = idx >> 8, rr = (idx >> 4) & 15, c4 = idx & 15;
      float4 v = *(const float4*)&bp[((size_t)(st * 8 + b) * 1024 + n0 + rr) * 64 + c4 * 4];
      feats[st][rr][16 + c4 * 4 + 0] = v.x; feats[st][rr][16 + c4 * 4 + 1] = v.y;
      feats[st][rr][16 + c4 * 4 + 2] = v.z; feats[st][rr][16 + c4 * 4 + 3] = v.w;
    }
  }
  if (MODE == 2 && tid < 16) {
    int n = n0 + tid;
    size_t xo = ((size_t)(b * T_ + t) * 1024 + n) * 16;
    float s = 0.0f;
    for (int d = 0; d < 16; ++d) s += fabsf(masks[xo + d]);
    Ms[tid] = (s > 1e-4f) ? 1.0f : 0.0f;
  }

  // --- MFMA K-loop (unchanged from r7) ---
  f32x4 acc[2][3];
#pragma unroll
  for (int rt = 0; rt < 2; ++rt)
#pragma unroll
    for (int ci = 0; ci < 3; ++ci) acc[rt][ci] = (f32x4){0.f, 0.f, 0.f, 0.f};

#define GLD(SRC, SLOT, BUF)                                                                   \
  __builtin_amdgcn_global_load_lds(                                                           \
      (const __attribute__((address_space(1))) void*)(SRC),                                   \
      (__attribute__((address_space(3))) void*)(stg + ((BUF)*NTILE + (SLOT)) * 512), 16, 0, 0)

#define STAGE(BUF, K0)                                                                        \
  {                                                                                           \
    if (w < 2) GLD(ag + (K0), w, BUF);                                                        \
    GLD(bs0 + (K0), 2 + w, BUF);                                                              \
    GLD(bs1 + (K0), 2 + w + 4, BUF);                                                          \
    if (NT == 9 && w == 0) GLD(bs2 + (K0), 2 + 8, BUF);                                       \
  }

  int cur = 0;
  STAGE(0, 0)
  __syncthreads();
  for (int step = 0; step < 32; ++step) {
    const int nxt = cur ^ 1;
    if (step < 31) STAGE(nxt, (step + 1) * 32)
    short8 a0f = *(const short8*)&stg[(cur * NTILE + 0) * 512 + l * 8];
    short8 a1f = *(const short8*)&stg[(cur * NTILE + 1) * 512 + l * 8];
    short8 b0f = *(const short8*)&stg[(cur * NTILE + 2 + w) * 512 + l * 8];
    short8 b1f = *(const short8*)&stg[(cur * NTILE + 2 + w + 4) * 512 + l * 8];
    acc[0][0] = __builtin_amdgcn_mfma_f32_16x16x32_bf16(a0f, b0f, acc[0][0], 0, 0, 0);
    acc[1][0] = __builtin_amdgcn_mfma_f32_16x16x32_bf16(a1f, b0f, acc[1][0], 0, 0, 0);
    acc[0][1] = __builtin_amdgcn_mfma_f32_16x16x32_bf16(a0f, b1f, acc[0][1], 0, 0, 0);
    acc[1][1] = __builtin_amdgcn_mfma_f32_16x16x32_bf16(a1f, b1f, acc[1][1], 0, 0, 0);
    if (NT == 9 && w == 0) {
      short8 b2f = *(const short8*)&stg[(cur * NTILE + 2 + 8) * 512 + l * 8];
      acc[0][2] = __builtin_amdgcn_mfma_f32_16x16x32_bf16(a0f, b2f, acc[0][2], 0, 0, 0);
      acc[1][2] = __builtin_amdgcn_mfma_f32_16x16x32_bf16(a1f, b2f, acc[1][2], 0, 0, 0);
    }
    __syncthreads();
    cur = nxt;
  }
#undef STAGE
#undef GLD

  // --- fragments -> feats ---
#pragma unroll
  for (int ci = 0; ci < 3; ++ci) {
    if (ci < bcnt) {
      const int ct = w + ci * 4;
#pragma unroll
      for (int rt = 0; rt < 2; ++rt) {
#pragma unroll
        for (int j = 0; j < 4; ++j) {
          float v = acc[rt][ci][j];
          int row = lk * 4 + j;
          if (MODE == 0) {
            int st = ct >> 2;
            feats[st][row][64 + rt * 64 + (ct & 3) * 16 + lr] = v;
          } else {
            if (ct == 0) {
              int col = 80 + rt * 80 + lr;
              feats[0][row][col] = v;
              feats[1][row][col] = v;
            } else {
              int st = (ct <= 4) ? 0 : 1;
              int cl = (ct <= 4) ? (ct - 1) : (ct - 5);
              feats[st][row][80 + rt * 80 + 16 + cl * 16 + lr] = v;
            }
          }
        }
      }
    }
  }
  __syncthreads();

  // ================= tails (fp32, unchanged) =================
  const int r_ = tid >> 4, cq = tid & 15;

  if (MODE == 0) {
    for (int st = 0; st < 2; ++st) {
      const float* W1 = st ? W1z : W1h;
      const float* B1 = st ? b1z : b1h;
      const float* W2 = st ? W2z : W2h;
      const float* B2 = st ? b2z : b2h;
      float a4[4] = {0, 0, 0, 0};
      for (int kc = 0; kc < NCHK; ++kc) {
        __syncthreads();
        for (int idx = tid; idx < 1024; idx += 256) {
          int k = idx >> 4, c4 = idx & 15;
          *(float4*)&Wcs[k * 68 + c4 * 4] = *(const float4*)&W1[(size_t)(kc * 64 + k) * 64 + c4 * 4];
        }
        __syncthreads();
#pragma unroll 8
        for (int k = 0; k < 64; ++k) {
          float f = feats[st][r_][kc * 64 + k];
          float4 w4 = *(float4*)&Wcs[k * 68 + cq * 4];
          a4[0] += f * w4.x; a4[1] += f * w4.y; a4[2] += f * w4.z; a4[3] += f * w4.w;
        }
      }
#pragma unroll
      for (int j = 0; j < 4; ++j) T1[r_ * 68 + cq * 4 + j] = tanhf(a4[j] + B1[cq * 4 + j]);
      __syncthreads();
      for (int idx = tid; idx < 1024; idx += 256) {
        int k = idx >> 4, c4 = idx & 15;
        *(float4*)&Wcs[k * 68 + c4 * 4] = *(const float4*)&W2[(size_t)k * 64 + c4 * 4];
      }
      __syncthreads();
      float o4[4] = {0, 0, 0, 0};
#pragma unroll 8
      for (int k = 0; k < 64; ++k) {
        float f = T1[r_ * 68 + k];
        float4 w4 = *(float4*)&Wcs[k * 68 + cq * 4];
        o4[0] += f * w4.x; o4[1] += f * w4.y; o4[2] += f * w4.z; o4[3] += f * w4.w;
      }
      size_t g = ((size_t)(st * 8 + b) * 1024 + n0 + r_) * 64 + cq * 4;
#pragma unroll
      for (int j = 0; j < 4; ++j) {
        float ns = S[g + j] + 0.025f * tanhf(o4[j] + B2[cq * 4 + j]);
        S[g + j] = ns;
        Ts[st][cq * 4 + j][r_] = ns;
      }
      __syncthreads();
    }
  } else if (MODE == 1) {
    for (int st = 0; st < 2; ++st) {
      const float* W1 = st ? W1z : W1h;
      const float* B1 = st ? b1z : b1h;
      float a8[8] = {0, 0, 0, 0, 0, 0, 0, 0};
      for (int kc = 0; kc < NCHK; ++kc) {
        __syncthreads();
        for (int idx = tid; idx < 1536; idx += 256) {
          int k = idx >> 5, c4 = idx & 31;
          *(float4*)&Wcs[k * 132 + c4 * 4] = *(const float4*)&W1[(size_t)(kc * 48 + k) * 128 + c4 * 4];
        }
        __syncthreads();
#pragma unroll 8
        for (int k = 0; k < 48; ++k) {
          float f = feats[st][r_][kc * 48 + k];
          float4 wA = *(float4*)&Wcs[k * 132 + cq * 8];
          float4 wB = *(float4*)&Wcs[k * 132 + cq * 8 + 4];
          a8[0] += f * wA.x; a8[1] += f * wA.y; a8[2] += f * wA.z; a8[3] += f * wA.w;
          a8[4] += f * wB.x; a8[5] += f * wB.y; a8[6] += f * wB.z; a8[7] += f * wB.w;
        }
      }
      size_t g = ((size_t)(st * 8 + b) * 1024 + n0 + r_) * 64;
      if (cq < 8) {
#pragma unroll
        for (int j = 0; j < 8; ++j) {
          int c = cq * 8 + j;
          float rr = sigm(a8[j] + B1[c]);
          float rhv = rr * feats[st][r_][16 + c];
          RH[g + c] = rhv;
          Ts[st][c][r_] = rhv;
        }
      } else {
#pragma unroll
        for (int j = 0; j < 8; ++j) {
          int c = (cq - 8) * 8 + j;
          U[g + c] = sigm(a8[j] + B1[64 + c]);
        }
      }
      __syncthreads();
    }
  } else {
    for (int st = 0; st < 2; ++st) {
      const float* W1 = st ? W1z : W1h;
      const float* B1 = st ? b1z : b1h;
      float a4[4] = {0, 0, 0, 0};
      for (int kc = 0; kc < NCHK; ++kc) {
        __syncthreads();
        for (int idx = tid; idx < 768; idx += 256) {
          int k = idx >> 4, c4 = idx & 15;
          *(float4*)&Wcs[k * 68 + c4 * 4] = *(const float4*)&W1[(size_t)(kc * 48 + k) * 64 + c4 * 4];
        }
        __syncthreads();
#pragma unroll 8
        for (int k = 0; k < 48; ++k) {
          float f = feats[st][r_][kc * 48 + k];
          float4 w4 = *(float4*)&Wcs[k * 68 + cq * 4];
          a4[0] += f * w4.x; a4[1] += f * w4.y; a4[2] += f * w4.z; a4[3] += f * w4.w;
        }
      }
      size_t g = ((size_t)(st * 8 + b) * 1024 + n0 + r_) * 64;
      float m = Ms[r_];
#pragma unroll
      for (int j = 0; j < 4; ++j) {
        int c = cq * 4 + j;
        float cc = tanhf(a4[j] + B1[c]);
        float h1 = S[g + c];
        float u = U[g + c];
        float h2 = u * h1 + (1.0f - u) * cc;
        float ns = h1 * (1.0f - m) + h2 * m;
        S[g + c] = ns;
        Ts[st][c][r_] = ns;
      }
      __syncthreads();
    }
  }

  // --- bf16 col-major mirror write ---
  {
    unsigned short* dstbuf = (MODE == 1) ? RHBout : SBw;
    int st = tid >> 7, c = (tid >> 1) & 63, p = tid & 1;
    float* tp = &Ts[st][c][p * 8];
    uint4 o;
    o.x = pk2(tp[0], tp[1]); o.y = pk2(tp[2], tp[3]);
    o.z = pk2(tp[4], tp[5]); o.w = pk2(tp[6], tp[7]);
    *(uint4*)(dstbuf + ((size_t)(st * 8 + b) * 64 + c) * 1024 + n0 + p * 8) = o;
  }

  // ================= OUT epilogue (mode-0 #2, t>=1): gate chain + projection =================
  if constexpr (MODE == 0 && OUT) {
    // zv_pre in Ts[1][c][r], hv_pre in Ts[0][c][r]; ping buffers in feats[0][r][0..67 / 96..163]
#define OLAYER(SRCEXPR, DSTOFF, WPTR, BPTR, ACT)                                     \
    __syncthreads();                                                                 \
    for (int idx = tid; idx < 1024; idx += 256) {                                    \
      int k = idx >> 4, c4 = idx & 15;                                               \
      *(float4*)&Wcs[k * 68 + c4 * 4] = *(const float4*)&(WPTR)[(size_t)k * 64 + c4 * 4]; \
    }                                                                                \
    if (tid < 64) gb[tid] = (BPTR)[tid];                                             \
    __syncthreads();                                                                 \
    {                                                                                \
      float a4[4] = {0, 0, 0, 0};                                                    \
      _Pragma("unroll 8") for (int k = 0; k < 64; ++k) {                             \
        float f = (SRCEXPR);                                                         \
        float4 w4 = *(float4*)&Wcs[k * 68 + cq * 4];                                 \
        a4[0] += f * w4.x; a4[1] += f * w4.y; a4[2] += f * w4.z; a4[3] += f * w4.w;  \
      }                                                                              \
      _Pragma("unroll") for (int j = 0; j < 4; ++j)                                  \
          feats[0][r_][(DSTOFF) + cq * 4 + j] = ACT(a4[j] + gb[cq * 4 + j]);         \
    }

    OLAYER(Ts[1][k][r_],           96, Wz1, bz1, tanhf)
    OLAYER(feats[0][r_][96 + k],    0, Wz2, bz2, tanhf)
    OLAYER(feats[0][r_][k],        96, Wz3, bz3, sigm)
#undef OLAYER
    // projection: out[b][t-1][n0+r_][cq] = sum_k hv[k]*g[k]*Wo[k][cq] + bo[cq]
    __syncthreads();
    for (int idx = tid; idx < 256; idx += 256)
      ((float4*)Wcs)[idx] = ((const float4*)Wo)[idx];
    if (tid < 16) gb[tid] = bo[tid];
    __syncthreads();
    float a0 = 0.0f;
#pragma unroll 8
    for (int k = 0; k < 64; ++k)
      a0 += Ts[0][k][r_] * feats[0][r_][96 + k] * Wcs[k * 16 + cq];
    size_t o = (((size_t)b * 39 + (t - 1)) * 1024 + n0 + r_) * 16 + cq;
    outp[o] = a0 + gb[cq];
  }
}

// ---------------------------------------------------------------- launch
extern "C" void kernel_launch(void* const* d_in, const int* in_sizes, int n_in,
                              void* d_out, int out_size, void* d_ws, size_t ws_size,
                              hipStream_t stream) {
  const float* values = (const float*)d_in[0];
  const float* masks  = (const float*)d_in[1];
  const float* A      = (const float*)d_in[2];
  const float* h0     = (const float*)d_in[3];
  const float* z0     = (const float*)d_in[4];
  const float* gV_Wg  = (const float*)d_in[5];
  const float* gV_bg  = (const float*)d_in[6];
  const float* gV_Wc  = (const float*)d_in[7];
  const float* gV_bc  = (const float*)d_in[8];
  const float* gG_Wg  = (const float*)d_in[9];
  const float* gG_bg  = (const float*)d_in[10];
  const float* gG_Wc  = (const float*)d_in[11];
  const float* gG_bc  = (const float*)d_in[12];
  const float* oV_W0  = (const float*)d_in[13];
  const float* oV_b0  = (const float*)d_in[14];
  const float* oV_Wout = (const float*)d_in[15];
  const float* oV_bout = (const float*)d_in[16];
  const float* oG_W0  = (const float*)d_in[17];
  const float* oG_b0  = (const float*)d_in[18];
  const float* oG_Wout = (const float*)d_in[19];
  const float* oG_bout = (const float*)d_in[20];
  const float* Wz1 = (const float*)d_in[21];
  const float* bz1 = (const float*)d_in[22];
  const float* Wz2 = (const float*)d_in[23];
  const float* bz2 = (const float*)d_in[24];
  const float* Wz3 = (const float*)d_in[25];
  const float* bz3 = (const float*)d_in[26];
  const float* Wo  = (const float*)d_in[27];
  const float* bo  = (const float*)d_in[28];
  float* out = (float*)d_out;

  if (ws_size < (size_t)79691776) return;
  char* ws = (char*)d_ws;
  float* S            = (float*)(ws + 0);
  float* RH           = (float*)(ws + 4194304);
  float* U            = (float*)(ws + 8388608);
  unsigned short* SBa = (unsigned short*)(ws + 12582912);
  unsigned short* SBb = (unsigned short*)(ws + 14680064);
  unsigned short* RHB = (unsigned short*)(ws + 16777216);
  unsigned short* XB  = (unsigned short*)(ws + 18874368);
  unsigned short* AS  = (unsigned short*)(ws + 29360128);
  unsigned short* ATB = (unsigned short*)(ws + 62914560);

  k_asA<<<4096, 256, 0, stream>>>(A, AS);
  k_tr<<<dim3(16, 16, 8), 256, 0, stream>>>(A, ATB);
  k_a2m<<<dim3(8, 16, 8), 256, 0, stream>>>(AS, ATB);
  k_init<<<4096, 256, 0, stream>>>(S, SBa, h0, z0);
  k_xb<<<dim3(320, 4), 256, 0, stream>>>(values, masks, XB);

  for (int t = 0; t < T_; ++t) {
    k_fused<0, 0><<<512, 256, 0, stream>>>(AS, XB, SBa, SBb, RHB, RHB, S, RH, U, values, masks,
                                           oV_W0, oV_b0, oV_Wout, oV_bout,
                                           oG_W0, oG_b0, oG_Wout, oG_bout,
                                           Wz1, bz1, Wz2, bz2, Wz3, bz3, Wo, bo, out, t);
    if (t == 0)
      k_fused<0, 0><<<512, 256, 0, stream>>>(AS, XB, SBb, SBa, RHB, RHB, S, RH, U, values, masks,
                                             oV_W0, oV_b0, oV_Wout, oV_bout,
                                             oG_W0, oG_b0, oG_Wout, oG_bout,
                                             Wz1, bz1, Wz2, bz2, Wz3, bz3, Wo, bo, out, t);
    else
      k_fused<0, 1><<<512, 256, 0, stream>>>(AS, XB, SBb, SBa, RHB, RHB, S, RH, U, values, masks,
                                             oV_W0, oV_b0, oV_Wout, oV_bout,
                                             oG_W0, oG_b0, oG_Wout, oG_bout,
                                             Wz1, bz1, Wz2, bz2, Wz3, bz3, Wo, bo, out, t);
    if (t < T_ - 1) {
      k_fused<1, 0><<<512, 256, 0, stream>>>(AS, XB, SBa, SBb, RHB, RHB, S, RH, U, values, masks,
                                             gV_Wg, gV_bg, nullptr, nullptr,
                                             gG_Wg, gG_bg, nullptr, nullptr,
                                             Wz1, bz1, Wz2, bz2, Wz3, bz3, Wo, bo, out, t);
      k_fused<2, 0><<<512, 256, 0, stream>>>(AS, XB, SBa, SBa, RHB, RHB, S, RH, U, values, masks,
                                             gV_Wc, gV_bc, nullptr, nullptr,
                                             gG_Wc, gG_bc, nullptr, nullptr,
                                             Wz1, bz1, Wz2, bz2, Wz3, bz3, Wo, bo, out, t);
    }
  }
}